// Round 1
// baseline (745.311 us; speedup 1.0000x reference)
//
#include <hip/hip_runtime.h>
#include <math.h>

#define NEG_SLOPE 0.2f

static __device__ __forceinline__ float lrelu(float x) { return x > 0.f ? x : NEG_SLOPE * x; }
static __device__ __forceinline__ float elu1(float x)  { return x > 0.f ? x : (expf(x) - 1.f); }

// ---------------- CSR build (by dst), reused for all 3 layers ----------------
__global__ void count_kernel(const int* __restrict__ ei, int* __restrict__ counts, int E, int E2) {
    int i = blockIdx.x * blockDim.x + threadIdx.x;
    if (i >= E2) return;
    int dst = (i < E) ? ei[E + i] : (i - E);
    atomicAdd(&counts[dst], 1);
}

__global__ __launch_bounds__(1024) void scan_kernel(const int* __restrict__ counts, int* __restrict__ row_start, int n) {
    __shared__ int sums[1024];
    int t = threadIdx.x;
    int chunk = (n + 1023) / 1024;
    int begin = t * chunk;
    int end = begin + chunk; if (end > n) end = n;
    int s = 0;
    for (int i = begin; i < end && i < n; i++) s += counts[i];
    sums[t] = s;
    __syncthreads();
    for (int off = 1; off < 1024; off <<= 1) {
        int v = 0;
        if (t >= off) v = sums[t - off];
        __syncthreads();
        if (t >= off) sums[t] += v;
        __syncthreads();
    }
    int prefix = (t == 0) ? 0 : sums[t - 1];
    for (int i = begin; i < end && i < n; i++) { row_start[i] = prefix; prefix += counts[i]; }
    if (end == n) row_start[n] = prefix;   // total (all covering/empty tail threads write same value)
}

__global__ void fill_kernel(const int* __restrict__ ei, const int* __restrict__ row_start,
                            int* __restrict__ fillc, int* __restrict__ eid, int E, int E2) {
    int i = blockIdx.x * blockDim.x + threadIdx.x;
    if (i >= E2) return;
    int dst = (i < E) ? ei[E + i] : (i - E);
    int pos = atomicAdd(&fillc[dst], 1);
    eid[row_start[dst] + pos] = i;
}

// ---------------- GEMM1: h1[M,256] = x[M,128] @ W1[128,256] (fp32) ----------------
__global__ __launch_bounds__(256) void gemm1_kernel(const float* __restrict__ A, const float* __restrict__ B,
                                                    float* __restrict__ C, int M) {
    __shared__ float As[16][64];  // [k][m]
    __shared__ float Bs[16][64];  // [k][n]
    int t = threadIdx.x;
    int tx = t & 15, ty = t >> 4;
    int row0 = blockIdx.x * 64, col0 = blockIdx.y * 64;
    float acc[4][4] = {};
    for (int k0 = 0; k0 < 128; k0 += 16) {
        {   // A tile: 64 rows x 16 k; thread: row=t>>2, k-seg=t&3
            int r = t >> 2, sg = t & 3;
            int grow = row0 + r; if (grow >= M) grow = M - 1;
            const float4 av = *(const float4*)&A[(size_t)grow * 128 + k0 + sg * 4];
            As[sg * 4 + 0][r] = av.x; As[sg * 4 + 1][r] = av.y;
            As[sg * 4 + 2][r] = av.z; As[sg * 4 + 3][r] = av.w;
        }
        {   // B tile: 16 k x 64 n; thread: k=t>>4, n-seg=t&15
            int kk = t >> 4, ns = t & 15;
            *(float4*)&Bs[kk][ns * 4] = *(const float4*)&B[(size_t)(k0 + kk) * 256 + col0 + ns * 4];
        }
        __syncthreads();
        #pragma unroll
        for (int k = 0; k < 16; k++) {
            float4 a4 = *(float4*)&As[k][ty * 4];
            float4 b4 = *(float4*)&Bs[k][tx * 4];
            float av[4] = {a4.x, a4.y, a4.z, a4.w};
            float bv[4] = {b4.x, b4.y, b4.z, b4.w};
            #pragma unroll
            for (int i = 0; i < 4; i++)
                #pragma unroll
                for (int j = 0; j < 4; j++)
                    acc[i][j] += av[i] * bv[j];
        }
        __syncthreads();
    }
    #pragma unroll
    for (int i = 0; i < 4; i++) {
        int r = row0 + ty * 4 + i;
        if (r < M) {
            float4 o = make_float4(acc[i][0], acc[i][1], acc[i][2], acc[i][3]);
            *(float4*)&C[(size_t)r * 256 + col0 + tx * 4] = o;
        }
    }
}

// ---------------- alpha1: per (node, head) dot with a_src1/a_dst1 ----------------
__global__ void alpha1_kernel(const float* __restrict__ h1, const float* __restrict__ a_src,
                              const float* __restrict__ a_dst, float* __restrict__ asrc,
                              float* __restrict__ adst, int N) {
    int i = blockIdx.x * blockDim.x + threadIdx.x;
    if (i >= N * 8) return;
    int n = i >> 3, h = i & 7;
    const float* hp = &h1[(size_t)n * 256 + h * 32];
    const float* as = &a_src[h * 32];
    const float* ad = &a_dst[h * 32];
    float s1 = 0.f, s2 = 0.f;
    #pragma unroll
    for (int f = 0; f < 32; f++) { float v = hp[f]; s1 += v * as[f]; s2 += v * ad[f]; }
    asrc[i] = s1; adst[i] = s2;
}

// ---------------- agg1: one wave per node, 64 lanes x float4 = 256 features ----------------
__global__ __launch_bounds__(256) void agg1_kernel(const float* __restrict__ h1, const float* __restrict__ asrc,
                                                   const float* __restrict__ adst, const int* __restrict__ row_start,
                                                   const int* __restrict__ eid, const int* __restrict__ ei,
                                                   const float* __restrict__ b1, float* __restrict__ h1p,
                                                   int N, int E) {
    int node = blockIdx.x * 4 + (threadIdx.x >> 6);
    if (node >= N) return;
    int lane = threadIdx.x & 63;
    int h = lane >> 3;                       // head = (4*lane)/32
    float adn = adst[node * 8 + h];
    int rs = row_start[node], re = row_start[node + 1];
    float mx = -INFINITY;
    for (int j = rs; j < re; j++) {
        int e = eid[j];
        int s = (e < E) ? ei[e] : (e - E);
        mx = fmaxf(mx, lrelu(asrc[s * 8 + h] + adn));
    }
    float4 acc = make_float4(0.f, 0.f, 0.f, 0.f);
    float den = 0.f;
    for (int j = rs; j < re; j++) {
        int e = eid[j];
        int s = (e < E) ? ei[e] : (e - E);
        float w = __expf(lrelu(asrc[s * 8 + h] + adn) - mx);
        den += w;
        const float4 hv = *(const float4*)&h1[(size_t)s * 256 + lane * 4];
        acc.x += w * hv.x; acc.y += w * hv.y; acc.z += w * hv.z; acc.w += w * hv.w;
    }
    float inv = 1.f / den;
    int o = lane * 4;
    float4 r;
    r.x = elu1(acc.x * inv + b1[o + 0]);
    r.y = elu1(acc.y * inv + b1[o + 1]);
    r.z = elu1(acc.z * inv + b1[o + 2]);
    r.w = elu1(acc.w * inv + b1[o + 3]);
    *(float4*)&h1p[(size_t)node * 256 + o] = r;
}

// ---------------- GEMM2 + alpha2: h2[N,16] = h1p[N,256] @ W2[256,16]; alpha scalars ----------------
__global__ __launch_bounds__(256) void gemm2_kernel(const float* __restrict__ X, const float* __restrict__ W2,
                                                    const float* __restrict__ a_src2, const float* __restrict__ a_dst2,
                                                    float* __restrict__ h2, float* __restrict__ asrc2,
                                                    float* __restrict__ adst2, int N) {
    __shared__ float ws[256 * 16];
    __shared__ float xs[16][256];
    int t = threadIdx.x;
    #pragma unroll
    for (int j = 0; j < 16; j++) ws[j * 256 + t] = W2[j * 256 + t];
    int base = blockIdx.x * 16;
    #pragma unroll
    for (int j = 0; j < 16; j++) {
        int n = base + j;
        xs[j][t] = (n < N) ? X[(size_t)n * 256 + t] : 0.f;
    }
    __syncthreads();
    int nl = t >> 4, c = t & 15;
    int n = base + nl;
    float acc = 0.f;
    #pragma unroll 8
    for (int k = 0; k < 256; k++) acc += xs[nl][k] * ws[k * 16 + c];
    float s1 = acc * a_src2[c];
    float s2 = acc * a_dst2[c];
    #pragma unroll
    for (int off = 8; off >= 1; off >>= 1) { s1 += __shfl_xor(s1, off, 16); s2 += __shfl_xor(s2, off, 16); }
    if (n < N) {
        h2[n * 16 + c] = acc;
        if (c == 0) { asrc2[n] = s1; adst2[n] = s2; }
    }
}

// ---------------- agg2: 16 lanes per node ----------------
__global__ __launch_bounds__(256) void agg2_kernel(const float* __restrict__ h2, const float* __restrict__ asrc2,
                                                   const float* __restrict__ adst2, const int* __restrict__ row_start,
                                                   const int* __restrict__ eid, const int* __restrict__ ei,
                                                   const float* __restrict__ b2, float* __restrict__ h3,
                                                   int N, int E) {
    int node = blockIdx.x * 16 + (threadIdx.x >> 4);
    if (node >= N) return;
    int c = threadIdx.x & 15;
    float adn = adst2[node];
    int rs = row_start[node], re = row_start[node + 1];
    float mx = -INFINITY;
    for (int j = rs; j < re; j++) {
        int e = eid[j];
        int s = (e < E) ? ei[e] : (e - E);
        mx = fmaxf(mx, lrelu(asrc2[s] + adn));
    }
    float acc = 0.f, den = 0.f;
    for (int j = rs; j < re; j++) {
        int e = eid[j];
        int s = (e < E) ? ei[e] : (e - E);
        float w = __expf(lrelu(asrc2[s] + adn) - mx);
        den += w;
        acc += w * h2[s * 16 + c];
    }
    h3[node * 16 + c] = elu1(acc / den + b2[c]);
}

// ---------------- dinv for GCN ----------------
__global__ void dinv_kernel(const int* __restrict__ counts, float* __restrict__ dinv, int N) {
    int i = blockIdx.x * blockDim.x + threadIdx.x;
    if (i >= N) return;
    dinv[i] = rsqrtf((float)counts[i]);   // counts >= 1 due to self-loop
}

// ---------------- GEMM3: h4[N,16] = h3[N,16] @ W3[16,16] ----------------
__global__ __launch_bounds__(256) void gemm3_kernel(const float* __restrict__ h3, const float* __restrict__ W3,
                                                    float* __restrict__ h4, int N) {
    __shared__ float ws[256];
    __shared__ float xs[16][16];
    int t = threadIdx.x;
    ws[t] = W3[t];
    int base = blockIdx.x * 16;
    {
        int n = base + (t >> 4);
        xs[t >> 4][t & 15] = (n < N) ? h3[n * 16 + (t & 15)] : 0.f;
    }
    __syncthreads();
    int nl = t >> 4, c = t & 15;
    int n = base + nl;
    float acc = 0.f;
    #pragma unroll
    for (int k = 0; k < 16; k++) acc += xs[nl][k] * ws[k * 16 + c];
    if (n < N) h4[n * 16 + c] = acc;
}

// ---------------- agg3 (GCN): out[n] = dinv[n] * sum dinv[s]*h4[s] + b3 ----------------
__global__ __launch_bounds__(256) void agg3_kernel(const float* __restrict__ h4, const float* __restrict__ dinv,
                                                   const int* __restrict__ row_start, const int* __restrict__ eid,
                                                   const int* __restrict__ ei, const float* __restrict__ b3,
                                                   float* __restrict__ out, int N, int E) {
    int node = blockIdx.x * 16 + (threadIdx.x >> 4);
    if (node >= N) return;
    int c = threadIdx.x & 15;
    int rs = row_start[node], re = row_start[node + 1];
    float acc = 0.f;
    for (int j = rs; j < re; j++) {
        int e = eid[j];
        int s = (e < E) ? ei[e] : (e - E);
        acc += dinv[s] * h4[s * 16 + c];
    }
    out[node * 16 + c] = acc * dinv[node] + b3[c];
}

extern "C" void kernel_launch(void* const* d_in, const int* in_sizes, int n_in,
                              void* d_out, int out_size, void* d_ws, size_t ws_size,
                              hipStream_t stream) {
    const float* x      = (const float*)d_in[0];
    const int*   ei     = (const int*)d_in[1];
    const float* W1     = (const float*)d_in[2];
    const float* a_src1 = (const float*)d_in[3];
    const float* a_dst1 = (const float*)d_in[4];
    const float* b1     = (const float*)d_in[5];
    const float* W2     = (const float*)d_in[6];
    const float* a_src2 = (const float*)d_in[7];
    const float* a_dst2 = (const float*)d_in[8];
    const float* b2     = (const float*)d_in[9];
    const float* W3     = (const float*)d_in[10];
    const float* b3     = (const float*)d_in[11];
    float* out = (float*)d_out;

    const int N  = in_sizes[0] / 128;   // 50000
    const int E  = in_sizes[1] / 2;     // 800000
    const int E2 = E + N;               // with self loops

    char* p = (char*)d_ws;
    auto alloc = [&](size_t bytes) -> void* {
        void* r = (void*)p;
        p += (bytes + 255) & ~(size_t)255;
        return r;
    };
    int*   counts = (int*)alloc((size_t)N * 4);
    int*   rowst  = (int*)alloc((size_t)(N + 1) * 4);
    int*   fillc  = (int*)alloc((size_t)N * 4);
    int*   eid    = (int*)alloc((size_t)E2 * 4);
    float* h1     = (float*)alloc((size_t)N * 256 * 4);
    float* h1p    = (float*)alloc((size_t)N * 256 * 4);
    float* as1    = (float*)alloc((size_t)N * 8 * 4);
    float* ad1    = (float*)alloc((size_t)N * 8 * 4);
    float* h2     = (float*)alloc((size_t)N * 16 * 4);
    float* as2    = (float*)alloc((size_t)N * 4);
    float* ad2    = (float*)alloc((size_t)N * 4);
    float* h3     = (float*)alloc((size_t)N * 16 * 4);
    float* h4     = (float*)alloc((size_t)N * 16 * 4);
    float* dinv   = (float*)alloc((size_t)N * 4);

    hipMemsetAsync(counts, 0, (size_t)N * 4, stream);
    hipMemsetAsync(fillc,  0, (size_t)N * 4, stream);

    count_kernel<<<(E2 + 255) / 256, 256, 0, stream>>>(ei, counts, E, E2);
    scan_kernel<<<1, 1024, 0, stream>>>(counts, rowst, N);
    fill_kernel<<<(E2 + 255) / 256, 256, 0, stream>>>(ei, rowst, fillc, eid, E, E2);

    gemm1_kernel<<<dim3((N + 63) / 64, 4), 256, 0, stream>>>(x, W1, h1, N);
    alpha1_kernel<<<(N * 8 + 255) / 256, 256, 0, stream>>>(h1, a_src1, a_dst1, as1, ad1, N);
    agg1_kernel<<<(N + 3) / 4, 256, 0, stream>>>(h1, as1, ad1, rowst, eid, ei, b1, h1p, N, E);

    gemm2_kernel<<<(N + 15) / 16, 256, 0, stream>>>(h1p, W2, a_src2, a_dst2, h2, as2, ad2, N);
    agg2_kernel<<<(N + 15) / 16, 256, 0, stream>>>(h2, as2, ad2, rowst, eid, ei, b2, h3, N, E);

    dinv_kernel<<<(N + 255) / 256, 256, 0, stream>>>(counts, dinv, N);
    gemm3_kernel<<<(N + 15) / 16, 256, 0, stream>>>(h3, W3, h4, N);
    agg3_kernel<<<(N + 15) / 16, 256, 0, stream>>>(h4, dinv, rowst, eid, ei, b3, out, N, E);
}

// Round 2
// 513.515 us; speedup vs baseline: 1.4514x; 1.4514x over previous
//
#include <hip/hip_runtime.h>
#include <math.h>

#define NEG_SLOPE 0.2f

static __device__ __forceinline__ float lrelu(float x) { return x > 0.f ? x : NEG_SLOPE * x; }
static __device__ __forceinline__ float elu1(float x)  { return x > 0.f ? x : (expf(x) - 1.f); }

// ---------------- CSR build (by dst), reused for all 3 layers ----------------
__global__ void count_kernel(const int* __restrict__ ei, int* __restrict__ counts, int E, int E2) {
    int i = blockIdx.x * blockDim.x + threadIdx.x;
    if (i >= E2) return;
    int dst = (i < E) ? ei[E + i] : (i - E);
    atomicAdd(&counts[dst], 1);
}

__global__ __launch_bounds__(1024) void scan_kernel(const int* __restrict__ counts, int* __restrict__ row_start, int n) {
    __shared__ int sums[1024];
    int t = threadIdx.x;
    int chunk = (n + 1023) / 1024;
    int begin = t * chunk;
    int end = begin + chunk; if (end > n) end = n;
    int s = 0;
    for (int i = begin; i < end && i < n; i++) s += counts[i];
    sums[t] = s;
    __syncthreads();
    for (int off = 1; off < 1024; off <<= 1) {
        int v = 0;
        if (t >= off) v = sums[t - off];
        __syncthreads();
        if (t >= off) sums[t] += v;
        __syncthreads();
    }
    int prefix = (t == 0) ? 0 : sums[t - 1];
    for (int i = begin; i < end && i < n; i++) { row_start[i] = prefix; prefix += counts[i]; }
    if (end == n) row_start[n] = prefix;
}

// writes the SOURCE node id directly in CSR slot (removes eid->ei indirection later)
__global__ void fill_kernel(const int* __restrict__ ei, const int* __restrict__ row_start,
                            int* __restrict__ fillc, int* __restrict__ srcs, int E, int E2) {
    int i = blockIdx.x * blockDim.x + threadIdx.x;
    if (i >= E2) return;
    int src, dst;
    if (i < E) { src = ei[i]; dst = ei[E + i]; }
    else       { src = i - E; dst = i - E; }
    int pos = atomicAdd(&fillc[dst], 1);
    srcs[row_start[dst] + pos] = src;
}

// ---------------- GEMM1: h1[M,256] = x[M,128] @ W1[128,256] (fp32) ----------------
__global__ __launch_bounds__(256) void gemm1_kernel(const float* __restrict__ A, const float* __restrict__ B,
                                                    float* __restrict__ C, int M) {
    __shared__ float As[16][64];  // [k][m]
    __shared__ float Bs[16][64];  // [k][n]
    int t = threadIdx.x;
    int tx = t & 15, ty = t >> 4;
    int row0 = blockIdx.x * 64, col0 = blockIdx.y * 64;
    float acc[4][4] = {};
    for (int k0 = 0; k0 < 128; k0 += 16) {
        {
            int r = t >> 2, sg = t & 3;
            int grow = row0 + r; if (grow >= M) grow = M - 1;
            const float4 av = *(const float4*)&A[(size_t)grow * 128 + k0 + sg * 4];
            As[sg * 4 + 0][r] = av.x; As[sg * 4 + 1][r] = av.y;
            As[sg * 4 + 2][r] = av.z; As[sg * 4 + 3][r] = av.w;
        }
        {
            int kk = t >> 4, ns = t & 15;
            *(float4*)&Bs[kk][ns * 4] = *(const float4*)&B[(size_t)(k0 + kk) * 256 + col0 + ns * 4];
        }
        __syncthreads();
        #pragma unroll
        for (int k = 0; k < 16; k++) {
            float4 a4 = *(float4*)&As[k][ty * 4];
            float4 b4 = *(float4*)&Bs[k][tx * 4];
            float av[4] = {a4.x, a4.y, a4.z, a4.w};
            float bv[4] = {b4.x, b4.y, b4.z, b4.w};
            #pragma unroll
            for (int i = 0; i < 4; i++)
                #pragma unroll
                for (int j = 0; j < 4; j++)
                    acc[i][j] += av[i] * bv[j];
        }
        __syncthreads();
    }
    #pragma unroll
    for (int i = 0; i < 4; i++) {
        int r = row0 + ty * 4 + i;
        if (r < M) {
            float4 o = make_float4(acc[i][0], acc[i][1], acc[i][2], acc[i][3]);
            *(float4*)&C[(size_t)r * 256 + col0 + tx * 4] = o;
        }
    }
}

// ---------------- alpha1: per (node, head) dot with a_src1/a_dst1, float4 ----------------
__global__ void alpha1_kernel(const float* __restrict__ h1, const float* __restrict__ a_src,
                              const float* __restrict__ a_dst, float* __restrict__ asrc,
                              float* __restrict__ adst, int N) {
    int i = blockIdx.x * blockDim.x + threadIdx.x;
    if (i >= N * 8) return;
    int h = i & 7;
    const float4* hp = (const float4*)&h1[(size_t)i * 32];   // n*256 + h*32 == i*32
    const float4* as = (const float4*)&a_src[h * 32];
    const float4* ad = (const float4*)&a_dst[h * 32];
    float s1 = 0.f, s2 = 0.f;
    #pragma unroll
    for (int f = 0; f < 8; f++) {
        float4 v = hp[f], a = as[f], d = ad[f];
        s1 += v.x * a.x + v.y * a.y + v.z * a.z + v.w * a.w;
        s2 += v.x * d.x + v.y * d.y + v.z * d.z + v.w * d.w;
    }
    asrc[i] = s1; adst[i] = s2;
}

// ---------------- agg1: one wave per node, single pass (no max), unroll 4 ----------------
__global__ __launch_bounds__(256) void agg1_kernel(const float* __restrict__ h1, const float* __restrict__ asrc,
                                                   const float* __restrict__ adst, const int* __restrict__ row_start,
                                                   const int* __restrict__ srcs, const float* __restrict__ b1,
                                                   float* __restrict__ h1p, int N) {
    int node = blockIdx.x * 4 + (threadIdx.x >> 6);
    if (node >= N) return;
    int lane = threadIdx.x & 63;
    int h = lane >> 3;
    float adn = adst[node * 8 + h];
    int rs = row_start[node], re = row_start[node + 1];
    float4 acc = make_float4(0.f, 0.f, 0.f, 0.f);
    float den = 0.f;
    int j = rs;
    for (; j + 3 < re; j += 4) {
        int s0 = srcs[j], s1 = srcs[j + 1], s2 = srcs[j + 2], s3 = srcs[j + 3];
        float a0 = asrc[s0 * 8 + h], a1 = asrc[s1 * 8 + h];
        float a2 = asrc[s2 * 8 + h], a3 = asrc[s3 * 8 + h];
        const float4 v0 = *(const float4*)&h1[(size_t)s0 * 256 + lane * 4];
        const float4 v1 = *(const float4*)&h1[(size_t)s1 * 256 + lane * 4];
        const float4 v2 = *(const float4*)&h1[(size_t)s2 * 256 + lane * 4];
        const float4 v3 = *(const float4*)&h1[(size_t)s3 * 256 + lane * 4];
        float w0 = __expf(lrelu(a0 + adn));
        float w1 = __expf(lrelu(a1 + adn));
        float w2 = __expf(lrelu(a2 + adn));
        float w3 = __expf(lrelu(a3 + adn));
        den += (w0 + w1) + (w2 + w3);
        acc.x += w0 * v0.x + w1 * v1.x + w2 * v2.x + w3 * v3.x;
        acc.y += w0 * v0.y + w1 * v1.y + w2 * v2.y + w3 * v3.y;
        acc.z += w0 * v0.z + w1 * v1.z + w2 * v2.z + w3 * v3.z;
        acc.w += w0 * v0.w + w1 * v1.w + w2 * v2.w + w3 * v3.w;
    }
    for (; j < re; j++) {
        int s = srcs[j];
        float w = __expf(lrelu(asrc[s * 8 + h] + adn));
        const float4 v = *(const float4*)&h1[(size_t)s * 256 + lane * 4];
        den += w;
        acc.x += w * v.x; acc.y += w * v.y; acc.z += w * v.z; acc.w += w * v.w;
    }
    float inv = 1.f / den;
    int o = lane * 4;
    float4 r;
    r.x = elu1(acc.x * inv + b1[o + 0]);
    r.y = elu1(acc.y * inv + b1[o + 1]);
    r.z = elu1(acc.z * inv + b1[o + 2]);
    r.w = elu1(acc.w * inv + b1[o + 3]);
    *(float4*)&h1p[(size_t)node * 256 + o] = r;
}

// ---------------- GEMM2 + alpha2 ----------------
__global__ __launch_bounds__(256) void gemm2_kernel(const float* __restrict__ X, const float* __restrict__ W2,
                                                    const float* __restrict__ a_src2, const float* __restrict__ a_dst2,
                                                    float* __restrict__ h2, float* __restrict__ asrc2,
                                                    float* __restrict__ adst2, int N) {
    __shared__ float ws[256 * 16];
    __shared__ float xs[16][256];
    int t = threadIdx.x;
    #pragma unroll
    for (int j = 0; j < 16; j++) ws[j * 256 + t] = W2[j * 256 + t];
    int base = blockIdx.x * 16;
    #pragma unroll
    for (int j = 0; j < 16; j++) {
        int n = base + j;
        xs[j][t] = (n < N) ? X[(size_t)n * 256 + t] : 0.f;
    }
    __syncthreads();
    int nl = t >> 4, c = t & 15;
    int n = base + nl;
    float acc = 0.f;
    #pragma unroll 8
    for (int k = 0; k < 256; k++) acc += xs[nl][k] * ws[k * 16 + c];
    float s1 = acc * a_src2[c];
    float s2 = acc * a_dst2[c];
    #pragma unroll
    for (int off = 8; off >= 1; off >>= 1) { s1 += __shfl_xor(s1, off, 16); s2 += __shfl_xor(s2, off, 16); }
    if (n < N) {
        h2[n * 16 + c] = acc;
        if (c == 0) { asrc2[n] = s1; adst2[n] = s2; }
    }
}

// ---------------- agg2: 16 lanes per node, single pass, unroll 4 ----------------
__global__ __launch_bounds__(256) void agg2_kernel(const float* __restrict__ h2, const float* __restrict__ asrc2,
                                                   const float* __restrict__ adst2, const int* __restrict__ row_start,
                                                   const int* __restrict__ srcs, const float* __restrict__ b2,
                                                   float* __restrict__ h3, int N) {
    int node = blockIdx.x * 16 + (threadIdx.x >> 4);
    if (node >= N) return;
    int c = threadIdx.x & 15;
    float adn = adst2[node];
    int rs = row_start[node], re = row_start[node + 1];
    float acc = 0.f, den = 0.f;
    int j = rs;
    for (; j + 3 < re; j += 4) {
        int s0 = srcs[j], s1 = srcs[j + 1], s2 = srcs[j + 2], s3 = srcs[j + 3];
        float a0 = asrc2[s0], a1 = asrc2[s1], a2 = asrc2[s2], a3 = asrc2[s3];
        float v0 = h2[s0 * 16 + c], v1 = h2[s1 * 16 + c];
        float v2 = h2[s2 * 16 + c], v3 = h2[s3 * 16 + c];
        float w0 = __expf(lrelu(a0 + adn));
        float w1 = __expf(lrelu(a1 + adn));
        float w2 = __expf(lrelu(a2 + adn));
        float w3 = __expf(lrelu(a3 + adn));
        den += (w0 + w1) + (w2 + w3);
        acc += w0 * v0 + w1 * v1 + w2 * v2 + w3 * v3;
    }
    for (; j < re; j++) {
        int s = srcs[j];
        float w = __expf(lrelu(asrc2[s] + adn));
        den += w;
        acc += w * h2[s * 16 + c];
    }
    h3[node * 16 + c] = elu1(acc / den + b2[c]);
}

// ---------------- dinv for GCN ----------------
__global__ void dinv_kernel(const int* __restrict__ counts, float* __restrict__ dinv, int N) {
    int i = blockIdx.x * blockDim.x + threadIdx.x;
    if (i >= N) return;
    dinv[i] = rsqrtf((float)counts[i]);
}

// ---------------- GEMM3: h4[N,16] = h3[N,16] @ W3[16,16] ----------------
__global__ __launch_bounds__(256) void gemm3_kernel(const float* __restrict__ h3, const float* __restrict__ W3,
                                                    float* __restrict__ h4, int N) {
    __shared__ float ws[256];
    __shared__ float xs[16][16];
    int t = threadIdx.x;
    ws[t] = W3[t];
    int base = blockIdx.x * 16;
    {
        int n = base + (t >> 4);
        xs[t >> 4][t & 15] = (n < N) ? h3[n * 16 + (t & 15)] : 0.f;
    }
    __syncthreads();
    int nl = t >> 4, c = t & 15;
    int n = base + nl;
    float acc = 0.f;
    #pragma unroll
    for (int k = 0; k < 16; k++) acc += xs[nl][k] * ws[k * 16 + c];
    if (n < N) h4[n * 16 + c] = acc;
}

// ---------------- agg3 (GCN), unroll 4 ----------------
__global__ __launch_bounds__(256) void agg3_kernel(const float* __restrict__ h4, const float* __restrict__ dinv,
                                                   const int* __restrict__ row_start, const int* __restrict__ srcs,
                                                   const float* __restrict__ b3, float* __restrict__ out, int N) {
    int node = blockIdx.x * 16 + (threadIdx.x >> 4);
    if (node >= N) return;
    int c = threadIdx.x & 15;
    int rs = row_start[node], re = row_start[node + 1];
    float acc = 0.f;
    int j = rs;
    for (; j + 3 < re; j += 4) {
        int s0 = srcs[j], s1 = srcs[j + 1], s2 = srcs[j + 2], s3 = srcs[j + 3];
        float d0 = dinv[s0], d1 = dinv[s1], d2 = dinv[s2], d3 = dinv[s3];
        float v0 = h4[s0 * 16 + c], v1 = h4[s1 * 16 + c];
        float v2 = h4[s2 * 16 + c], v3 = h4[s3 * 16 + c];
        acc += d0 * v0 + d1 * v1 + d2 * v2 + d3 * v3;
    }
    for (; j < re; j++) {
        int s = srcs[j];
        acc += dinv[s] * h4[s * 16 + c];
    }
    out[node * 16 + c] = acc * dinv[node] + b3[c];
}

extern "C" void kernel_launch(void* const* d_in, const int* in_sizes, int n_in,
                              void* d_out, int out_size, void* d_ws, size_t ws_size,
                              hipStream_t stream) {
    const float* x      = (const float*)d_in[0];
    const int*   ei     = (const int*)d_in[1];
    const float* W1     = (const float*)d_in[2];
    const float* a_src1 = (const float*)d_in[3];
    const float* a_dst1 = (const float*)d_in[4];
    const float* b1     = (const float*)d_in[5];
    const float* W2     = (const float*)d_in[6];
    const float* a_src2 = (const float*)d_in[7];
    const float* a_dst2 = (const float*)d_in[8];
    const float* b2     = (const float*)d_in[9];
    const float* W3     = (const float*)d_in[10];
    const float* b3     = (const float*)d_in[11];
    float* out = (float*)d_out;

    const int N  = in_sizes[0] / 128;   // 50000
    const int E  = in_sizes[1] / 2;     // 800000
    const int E2 = E + N;

    char* p = (char*)d_ws;
    auto alloc = [&](size_t bytes) -> void* {
        void* r = (void*)p;
        p += (bytes + 255) & ~(size_t)255;
        return r;
    };
    int*   counts = (int*)alloc((size_t)N * 4);
    int*   rowst  = (int*)alloc((size_t)(N + 1) * 4);
    int*   fillc  = (int*)alloc((size_t)N * 4);
    int*   srcs   = (int*)alloc((size_t)E2 * 4);
    float* h1     = (float*)alloc((size_t)N * 256 * 4);
    float* h1p    = (float*)alloc((size_t)N * 256 * 4);
    float* as1    = (float*)alloc((size_t)N * 8 * 4);
    float* ad1    = (float*)alloc((size_t)N * 8 * 4);
    float* h2     = (float*)alloc((size_t)N * 16 * 4);
    float* as2    = (float*)alloc((size_t)N * 4);
    float* ad2    = (float*)alloc((size_t)N * 4);
    float* h3     = (float*)alloc((size_t)N * 16 * 4);
    float* h4     = (float*)alloc((size_t)N * 16 * 4);
    float* dinv   = (float*)alloc((size_t)N * 4);

    hipMemsetAsync(counts, 0, (size_t)N * 4, stream);
    hipMemsetAsync(fillc,  0, (size_t)N * 4, stream);

    count_kernel<<<(E2 + 255) / 256, 256, 0, stream>>>(ei, counts, E, E2);
    scan_kernel<<<1, 1024, 0, stream>>>(counts, rowst, N);
    fill_kernel<<<(E2 + 255) / 256, 256, 0, stream>>>(ei, rowst, fillc, srcs, E, E2);

    gemm1_kernel<<<dim3((N + 63) / 64, 4), 256, 0, stream>>>(x, W1, h1, N);
    alpha1_kernel<<<(N * 8 + 255) / 256, 256, 0, stream>>>(h1, a_src1, a_dst1, as1, ad1, N);
    agg1_kernel<<<(N + 3) / 4, 256, 0, stream>>>(h1, as1, ad1, rowst, srcs, b1, h1p, N);

    gemm2_kernel<<<(N + 15) / 16, 256, 0, stream>>>(h1p, W2, a_src2, a_dst2, h2, as2, ad2, N);
    agg2_kernel<<<(N + 15) / 16, 256, 0, stream>>>(h2, as2, ad2, rowst, srcs, b2, h3, N);

    dinv_kernel<<<(N + 255) / 256, 256, 0, stream>>>(counts, dinv, N);
    gemm3_kernel<<<(N + 15) / 16, 256, 0, stream>>>(h3, W3, h4, N);
    agg3_kernel<<<(N + 15) / 16, 256, 0, stream>>>(h4, dinv, rowst, srcs, b3, out, N);
}

// Round 3
// 455.197 us; speedup vs baseline: 1.6373x; 1.1281x over previous
//
#include <hip/hip_runtime.h>
#include <math.h>

#define NEG_SLOPE 0.2f

static __device__ __forceinline__ float lrelu(float x) { return x > 0.f ? x : NEG_SLOPE * x; }
static __device__ __forceinline__ float elu1(float x)  { return x > 0.f ? x : (expf(x) - 1.f); }

// ---------------- CSR build (by dst), reused for all 3 layers ----------------
__global__ void count_kernel(const int* __restrict__ ei, int* __restrict__ counts, int E, int E2) {
    int i = blockIdx.x * blockDim.x + threadIdx.x;
    if (i >= E2) return;
    int dst = (i < E) ? ei[E + i] : (i - E);
    atomicAdd(&counts[dst], 1);
}

// phase A: per-256-tile sums
__global__ __launch_bounds__(256) void scanA_kernel(const int* __restrict__ counts, int* __restrict__ blocksum, int N) {
    __shared__ int red[256];
    int t = threadIdx.x;
    int i = blockIdx.x * 256 + t;
    int v = (i < N) ? counts[i] : 0;
    red[t] = v; __syncthreads();
    for (int off = 128; off >= 1; off >>= 1) {
        if (t < off) red[t] += red[t + off];
        __syncthreads();
    }
    if (t == 0) blocksum[blockIdx.x] = red[0];
}

// phase B: exclusive scan of block sums (single block, chunked for robustness)
__global__ __launch_bounds__(256) void scanB_kernel(int* __restrict__ bs, int NB) {
    __shared__ int sm[256];
    int t = threadIdx.x;
    int carry = 0;
    for (int b0 = 0; b0 < NB; b0 += 256) {
        int v = (b0 + t < NB) ? bs[b0 + t] : 0;
        sm[t] = v; __syncthreads();
        for (int off = 1; off < 256; off <<= 1) {
            int u = (t >= off) ? sm[t - off] : 0;
            __syncthreads();
            sm[t] += u;
            __syncthreads();
        }
        if (b0 + t < NB) bs[b0 + t] = carry + sm[t] - v;
        int tot = sm[255];
        __syncthreads();
        carry += tot;
    }
}

// phase C: per-tile exclusive scan + block offset -> row_start; fused dinv
__global__ __launch_bounds__(256) void scanC_kernel(const int* __restrict__ counts, const int* __restrict__ blocksum,
                                                    int* __restrict__ row_start, float* __restrict__ dinv, int N) {
    __shared__ int sm[256];
    int t = threadIdx.x;
    int i = blockIdx.x * 256 + t;
    int v = (i < N) ? counts[i] : 0;
    sm[t] = v; __syncthreads();
    for (int off = 1; off < 256; off <<= 1) {
        int u = (t >= off) ? sm[t - off] : 0;
        __syncthreads();
        sm[t] += u;
        __syncthreads();
    }
    if (i < N) {
        row_start[i] = blocksum[blockIdx.x] + sm[t] - v;
        dinv[i] = rsqrtf((float)v);   // v >= 1 due to self-loop
    }
    if (i == N - 1) row_start[N] = blocksum[blockIdx.x] + sm[t];
}

// writes the SOURCE node id directly in CSR slot
__global__ void fill_kernel(const int* __restrict__ ei, const int* __restrict__ row_start,
                            int* __restrict__ fillc, int* __restrict__ srcs, int E, int E2) {
    int i = blockIdx.x * blockDim.x + threadIdx.x;
    if (i >= E2) return;
    int src, dst;
    if (i < E) { src = ei[i]; dst = ei[E + i]; }
    else       { src = i - E; dst = i - E; }
    int pos = atomicAdd(&fillc[dst], 1);
    srcs[row_start[dst] + pos] = src;
}

// ---------------- GEMM1: h1[M,256] = x[M,128] @ W1[128,256], 128x128 tile, 8x8 micro ----------------
__global__ __launch_bounds__(256) void gemm1_kernel(const float* __restrict__ A, const float* __restrict__ B,
                                                    float* __restrict__ C, int M) {
    __shared__ float As[16][128];
    __shared__ float Bs[16][128];
    int t = threadIdx.x;
    int tx = t & 15, ty = t >> 4;
    int row0 = blockIdx.x * 128, col0 = blockIdx.y * 128;
    float acc[8][8] = {};
    for (int k0 = 0; k0 < 128; k0 += 16) {
        #pragma unroll
        for (int u = 0; u < 2; u++) {
            int idx = t * 2 + u;            // 0..511
            int r = idx >> 2, kc = idx & 3;
            int grow = row0 + r; if (grow >= M) grow = M - 1;
            float4 av = *(const float4*)&A[(size_t)grow * 128 + k0 + kc * 4];
            As[kc * 4 + 0][r] = av.x; As[kc * 4 + 1][r] = av.y;
            As[kc * 4 + 2][r] = av.z; As[kc * 4 + 3][r] = av.w;
        }
        #pragma unroll
        for (int u = 0; u < 2; u++) {
            int idx = t * 2 + u;
            int kk = idx >> 5, cc = idx & 31;
            *(float4*)&Bs[kk][cc * 4] = *(const float4*)&B[(size_t)(k0 + kk) * 256 + col0 + cc * 4];
        }
        __syncthreads();
        #pragma unroll
        for (int k = 0; k < 16; k++) {
            float a[8], b[8];
            *(float4*)&a[0] = *(float4*)&As[k][ty * 8];
            *(float4*)&a[4] = *(float4*)&As[k][ty * 8 + 4];
            *(float4*)&b[0] = *(float4*)&Bs[k][tx * 8];
            *(float4*)&b[4] = *(float4*)&Bs[k][tx * 8 + 4];
            #pragma unroll
            for (int i = 0; i < 8; i++)
                #pragma unroll
                for (int j = 0; j < 8; j++)
                    acc[i][j] += a[i] * b[j];
        }
        __syncthreads();
    }
    #pragma unroll
    for (int i = 0; i < 8; i++) {
        int r = row0 + ty * 8 + i;
        if (r < M) {
            *(float4*)&C[(size_t)r * 256 + col0 + tx * 8]     = make_float4(acc[i][0], acc[i][1], acc[i][2], acc[i][3]);
            *(float4*)&C[(size_t)r * 256 + col0 + tx * 8 + 4] = make_float4(acc[i][4], acc[i][5], acc[i][6], acc[i][7]);
        }
    }
}

// ---------------- alpha1: per (node, head) dot with a_src1/a_dst1, float4 ----------------
__global__ void alpha1_kernel(const float* __restrict__ h1, const float* __restrict__ a_src,
                              const float* __restrict__ a_dst, float* __restrict__ asrc,
                              float* __restrict__ adst, int N) {
    int i = blockIdx.x * blockDim.x + threadIdx.x;
    if (i >= N * 8) return;
    int h = i & 7;
    const float4* hp = (const float4*)&h1[(size_t)i * 32];
    const float4* as = (const float4*)&a_src[h * 32];
    const float4* ad = (const float4*)&a_dst[h * 32];
    float s1 = 0.f, s2 = 0.f;
    #pragma unroll
    for (int f = 0; f < 8; f++) {
        float4 v = hp[f], a = as[f], d = ad[f];
        s1 += v.x * a.x + v.y * a.y + v.z * a.z + v.w * a.w;
        s2 += v.x * d.x + v.y * d.y + v.z * d.z + v.w * d.w;
    }
    asrc[i] = s1; adst[i] = s2;
}

// ---------------- agg1 v3: wave/node, shfl-broadcast edge ids & weights ----------------
__global__ __launch_bounds__(256) void agg1_kernel(const float* __restrict__ h1, const float* __restrict__ asrc,
                                                   const float* __restrict__ adst, const int* __restrict__ row_start,
                                                   const int* __restrict__ srcs, const float* __restrict__ b1,
                                                   float* __restrict__ h1p, int N) {
    int node = blockIdx.x * 4 + (threadIdx.x >> 6);
    if (node >= N) return;
    int lane = threadIdx.x & 63;
    int h = lane >> 3, e8 = lane & 7;
    float adn = adst[node * 8 + h];
    int rs = row_start[node], re = row_start[node + 1];
    float4 acc = make_float4(0.f, 0.f, 0.f, 0.f);
    float den = 0.f;
    for (int base = rs; base < re; base += 64) {
        int cnt = re - base; if (cnt > 64) cnt = 64;
        int sv = 0;
        if (lane < cnt) sv = srcs[base + lane];
        int g = 0;
        for (; g + 8 <= cnt; g += 8) {
            // lane (h, e8) computes weight of edge g+e8 for head h
            int ss = __shfl(sv, g + e8);
            float wp = __expf(lrelu(asrc[ss * 8 + h] + adn));
            #pragma unroll
            for (int q = 0; q < 8; q++) {
                int s = __shfl(sv, g + q);
                float w = __shfl(wp, (h << 3) | q);
                const float4 v = *(const float4*)&h1[(size_t)s * 256 + lane * 4];
                acc.x += w * v.x; acc.y += w * v.y; acc.z += w * v.z; acc.w += w * v.w;
                den += w;
            }
        }
        if (g < cnt) {   // tail: < 8 edges
            int ep = g + e8;
            int epc = ep < cnt - 1 ? ep : cnt - 1;
            int ss = __shfl(sv, epc);                       // all lanes participate
            float wp = (ep < cnt) ? __expf(lrelu(asrc[ss * 8 + h] + adn)) : 0.f;
            #pragma unroll
            for (int q = 0; q < 8; q++) {
                if (g + q < cnt) {                          // wave-uniform branch
                    int s = __shfl(sv, g + q);
                    float w = __shfl(wp, (h << 3) | q);
                    const float4 v = *(const float4*)&h1[(size_t)s * 256 + lane * 4];
                    acc.x += w * v.x; acc.y += w * v.y; acc.z += w * v.z; acc.w += w * v.w;
                    den += w;
                }
            }
        }
    }
    float inv = 1.f / den;
    int o = lane * 4;
    float4 r;
    r.x = elu1(acc.x * inv + b1[o + 0]);
    r.y = elu1(acc.y * inv + b1[o + 1]);
    r.z = elu1(acc.z * inv + b1[o + 2]);
    r.w = elu1(acc.w * inv + b1[o + 3]);
    *(float4*)&h1p[(size_t)node * 256 + o] = r;
}

// ---------------- GEMM2 + alpha2: register-resident W2, broadcast X reads ----------------
__global__ __launch_bounds__(256) void gemm2_kernel(const float* __restrict__ X, const float* __restrict__ W2,
                                                    const float* __restrict__ a_src2, const float* __restrict__ a_dst2,
                                                    float* __restrict__ h2, float* __restrict__ asrc2,
                                                    float* __restrict__ adst2, int N) {
    int lane = threadIdx.x & 63;
    int c = lane & 15, kq = lane >> 4;
    int wid = blockIdx.x * (blockDim.x >> 6) + (threadIdx.x >> 6);
    int nwaves = gridDim.x * (blockDim.x >> 6);
    float w2r[64];
    #pragma unroll
    for (int i = 0; i < 64; i++) w2r[i] = W2[(kq * 64 + i) * 16 + c];
    float as_c = a_src2[c], ad_c = a_dst2[c];
    for (int n = wid; n < N; n += nwaves) {
        const float* xp = &X[(size_t)n * 256 + kq * 64];
        float acc = 0.f;
        #pragma unroll
        for (int i4 = 0; i4 < 16; i4++) {
            float4 xv = *(const float4*)&xp[i4 * 4];
            acc += xv.x * w2r[i4 * 4] + xv.y * w2r[i4 * 4 + 1] + xv.z * w2r[i4 * 4 + 2] + xv.w * w2r[i4 * 4 + 3];
        }
        acc += __shfl_xor(acc, 16);
        acc += __shfl_xor(acc, 32);     // all lanes: full dot for col c
        float s1 = acc * as_c, s2 = acc * ad_c;
        #pragma unroll
        for (int off = 1; off < 16; off <<= 1) { s1 += __shfl_xor(s1, off); s2 += __shfl_xor(s2, off); }
        if (kq == 0) h2[n * 16 + c] = acc;
        if (lane == 0) { asrc2[n] = s1; adst2[n] = s2; }
    }
}

// ---------------- agg2: wave/node, 4 edges in flight x 16 cols ----------------
__global__ __launch_bounds__(256) void agg2_kernel(const float* __restrict__ h2, const float* __restrict__ asrc2,
                                                   const float* __restrict__ adst2, const int* __restrict__ row_start,
                                                   const int* __restrict__ srcs, const float* __restrict__ b2,
                                                   float* __restrict__ h3, int N) {
    int node = blockIdx.x * 4 + (threadIdx.x >> 6);
    if (node >= N) return;
    int lane = threadIdx.x & 63;
    int q = lane >> 4, c = lane & 15;
    float adn = adst2[node];
    int rs = row_start[node], re = row_start[node + 1];
    float acc = 0.f, den = 0.f;
    for (int base = rs; base < re; base += 64) {
        int cnt = re - base; if (cnt > 64) cnt = 64;
        int sv = 0; float wv = 0.f;
        if (lane < cnt) { sv = srcs[base + lane]; wv = __expf(lrelu(asrc2[sv] + adn)); }
        int nit = (cnt + 3) >> 2;
        for (int it = 0; it < nit; it++) {
            int j = it * 4 + q;
            int s = __shfl(sv, j);
            float w = __shfl(wv, j);     // 0 for j >= cnt; s=0 is a safe row
            float v = h2[s * 16 + c];
            acc += w * v; den += w;
        }
    }
    acc += __shfl_xor(acc, 16); acc += __shfl_xor(acc, 32);
    den += __shfl_xor(den, 16); den += __shfl_xor(den, 32);
    if (q == 0) h3[node * 16 + c] = elu1(acc / den + b2[c]);
}

// ---------------- GEMM3: h4[N,16] = h3[N,16] @ W3[16,16] ----------------
__global__ __launch_bounds__(256) void gemm3_kernel(const float* __restrict__ h3, const float* __restrict__ W3,
                                                    float* __restrict__ h4, int N) {
    __shared__ float ws[256];
    __shared__ float xs[16][16];
    int t = threadIdx.x;
    ws[t] = W3[t];
    int base = blockIdx.x * 16;
    {
        int n = base + (t >> 4);
        xs[t >> 4][t & 15] = (n < N) ? h3[n * 16 + (t & 15)] : 0.f;
    }
    __syncthreads();
    int nl = t >> 4, c = t & 15;
    int n = base + nl;
    float acc = 0.f;
    #pragma unroll
    for (int k = 0; k < 16; k++) acc += xs[nl][k] * ws[k * 16 + c];
    if (n < N) h4[n * 16 + c] = acc;
}

// ---------------- agg3 (GCN): wave/node, 4 edges in flight ----------------
__global__ __launch_bounds__(256) void agg3_kernel(const float* __restrict__ h4, const float* __restrict__ dinv,
                                                   const int* __restrict__ row_start, const int* __restrict__ srcs,
                                                   const float* __restrict__ b3, float* __restrict__ out, int N) {
    int node = blockIdx.x * 4 + (threadIdx.x >> 6);
    if (node >= N) return;
    int lane = threadIdx.x & 63;
    int q = lane >> 4, c = lane & 15;
    int rs = row_start[node], re = row_start[node + 1];
    float acc = 0.f;
    for (int base = rs; base < re; base += 64) {
        int cnt = re - base; if (cnt > 64) cnt = 64;
        int sv = 0; float wv = 0.f;
        if (lane < cnt) { sv = srcs[base + lane]; wv = dinv[sv]; }
        int nit = (cnt + 3) >> 2;
        for (int it = 0; it < nit; it++) {
            int j = it * 4 + q;
            int s = __shfl(sv, j);
            float w = __shfl(wv, j);
            float v = h4[s * 16 + c];
            acc += w * v;
        }
    }
    acc += __shfl_xor(acc, 16); acc += __shfl_xor(acc, 32);
    if (q == 0) out[node * 16 + c] = acc * dinv[node] + b3[c];
}

extern "C" void kernel_launch(void* const* d_in, const int* in_sizes, int n_in,
                              void* d_out, int out_size, void* d_ws, size_t ws_size,
                              hipStream_t stream) {
    const float* x      = (const float*)d_in[0];
    const int*   ei     = (const int*)d_in[1];
    const float* W1     = (const float*)d_in[2];
    const float* a_src1 = (const float*)d_in[3];
    const float* a_dst1 = (const float*)d_in[4];
    const float* b1     = (const float*)d_in[5];
    const float* W2     = (const float*)d_in[6];
    const float* a_src2 = (const float*)d_in[7];
    const float* a_dst2 = (const float*)d_in[8];
    const float* b2     = (const float*)d_in[9];
    const float* W3     = (const float*)d_in[10];
    const float* b3     = (const float*)d_in[11];
    float* out = (float*)d_out;

    const int N  = in_sizes[0] / 128;   // 50000
    const int E  = in_sizes[1] / 2;     // 800000
    const int E2 = E + N;
    const int NB = (N + 255) / 256;

    char* p = (char*)d_ws;
    auto alloc = [&](size_t bytes) -> void* {
        void* r = (void*)p;
        p += (bytes + 255) & ~(size_t)255;
        return r;
    };
    int*   counts = (int*)alloc((size_t)N * 4);
    int*   rowst  = (int*)alloc((size_t)(N + 1) * 4);
    int*   fillc  = (int*)alloc((size_t)N * 4);
    int*   srcs   = (int*)alloc((size_t)E2 * 4);
    int*   bsum   = (int*)alloc((size_t)NB * 4);
    float* h1     = (float*)alloc((size_t)N * 256 * 4);
    float* h1p    = (float*)alloc((size_t)N * 256 * 4);
    float* as1    = (float*)alloc((size_t)N * 8 * 4);
    float* ad1    = (float*)alloc((size_t)N * 8 * 4);
    float* h2     = (float*)alloc((size_t)N * 16 * 4);
    float* as2    = (float*)alloc((size_t)N * 4);
    float* ad2    = (float*)alloc((size_t)N * 4);
    float* h3     = (float*)alloc((size_t)N * 16 * 4);
    float* h4     = (float*)alloc((size_t)N * 16 * 4);
    float* dinv   = (float*)alloc((size_t)N * 4);

    hipMemsetAsync(counts, 0, (size_t)N * 4, stream);
    hipMemsetAsync(fillc,  0, (size_t)N * 4, stream);

    count_kernel<<<(E2 + 255) / 256, 256, 0, stream>>>(ei, counts, E, E2);
    scanA_kernel<<<NB, 256, 0, stream>>>(counts, bsum, N);
    scanB_kernel<<<1, 256, 0, stream>>>(bsum, NB);
    scanC_kernel<<<NB, 256, 0, stream>>>(counts, bsum, rowst, dinv, N);
    fill_kernel<<<(E2 + 255) / 256, 256, 0, stream>>>(ei, rowst, fillc, srcs, E, E2);

    gemm1_kernel<<<dim3((N + 127) / 128, 2), 256, 0, stream>>>(x, W1, h1, N);
    alpha1_kernel<<<(N * 8 + 255) / 256, 256, 0, stream>>>(h1, a_src1, a_dst1, as1, ad1, N);
    agg1_kernel<<<(N + 3) / 4, 256, 0, stream>>>(h1, as1, ad1, rowst, srcs, b1, h1p, N);

    gemm2_kernel<<<1024, 256, 0, stream>>>(h1p, W2, a_src2, a_dst2, h2, as2, ad2, N);
    agg2_kernel<<<(N + 3) / 4, 256, 0, stream>>>(h2, as2, ad2, rowst, srcs, b2, h3, N);

    gemm3_kernel<<<(N + 15) / 16, 256, 0, stream>>>(h3, W3, h4, N);
    agg3_kernel<<<(N + 3) / 4, 256, 0, stream>>>(h4, dinv, rowst, srcs, b3, out, N);
}

// Round 4
// 445.406 us; speedup vs baseline: 1.6733x; 1.0220x over previous
//
#include <hip/hip_runtime.h>
#include <math.h>

#define NEG_SLOPE 0.2f

static __device__ __forceinline__ float lrelu(float x) { return x > 0.f ? x : NEG_SLOPE * x; }
static __device__ __forceinline__ float elu1(float x)  { return x > 0.f ? x : (expf(x) - 1.f); }

// ---------------- CSR build (by dst), reused for all 3 layers ----------------
__global__ void count_kernel(const int* __restrict__ ei, int* __restrict__ counts, int E, int E2) {
    int i = blockIdx.x * blockDim.x + threadIdx.x;
    if (i >= E2) return;
    int dst = (i < E) ? ei[E + i] : (i - E);
    atomicAdd(&counts[dst], 1);
}

// phase A: per-256-tile sums
__global__ __launch_bounds__(256) void scanA_kernel(const int* __restrict__ counts, int* __restrict__ blocksum, int N) {
    __shared__ int red[256];
    int t = threadIdx.x;
    int i = blockIdx.x * 256 + t;
    int v = (i < N) ? counts[i] : 0;
    red[t] = v; __syncthreads();
    for (int off = 128; off >= 1; off >>= 1) {
        if (t < off) red[t] += red[t + off];
        __syncthreads();
    }
    if (t == 0) blocksum[blockIdx.x] = red[0];
}

// phase B: exclusive scan of block sums (single block, chunked)
__global__ __launch_bounds__(256) void scanB_kernel(int* __restrict__ bs, int NB) {
    __shared__ int sm[256];
    int t = threadIdx.x;
    int carry = 0;
    for (int b0 = 0; b0 < NB; b0 += 256) {
        int v = (b0 + t < NB) ? bs[b0 + t] : 0;
        sm[t] = v; __syncthreads();
        for (int off = 1; off < 256; off <<= 1) {
            int u = (t >= off) ? sm[t - off] : 0;
            __syncthreads();
            sm[t] += u;
            __syncthreads();
        }
        if (b0 + t < NB) bs[b0 + t] = carry + sm[t] - v;
        int tot = sm[255];
        __syncthreads();
        carry += tot;
    }
}

// phase C: row_start + fillc(start positions) + dinv
__global__ __launch_bounds__(256) void scanC_kernel(const int* __restrict__ counts, const int* __restrict__ blocksum,
                                                    int* __restrict__ row_start, int* __restrict__ fillc,
                                                    float* __restrict__ dinv, int N) {
    __shared__ int sm[256];
    int t = threadIdx.x;
    int i = blockIdx.x * 256 + t;
    int v = (i < N) ? counts[i] : 0;
    sm[t] = v; __syncthreads();
    for (int off = 1; off < 256; off <<= 1) {
        int u = (t >= off) ? sm[t - off] : 0;
        __syncthreads();
        sm[t] += u;
        __syncthreads();
    }
    if (i < N) {
        int rsv = blocksum[blockIdx.x] + sm[t] - v;
        row_start[i] = rsv;
        fillc[i] = rsv;
        dinv[i] = rsqrtf((float)v);   // v >= 1 due to self-loop
    }
    if (i == N - 1) row_start[N] = blocksum[blockIdx.x] + sm[t];
}

// scatter src ids into CSR slots (fillc pre-seeded with row starts)
__global__ void fill_kernel(const int* __restrict__ ei, int* __restrict__ fillc,
                            int* __restrict__ srcs, int E, int E2) {
    int i = blockIdx.x * blockDim.x + threadIdx.x;
    if (i >= E2) return;
    int src, dst;
    if (i < E) { src = ei[i]; dst = ei[E + i]; }
    else       { src = i - E; dst = i - E; }
    int pos = atomicAdd(&fillc[dst], 1);
    srcs[pos] = src;
}

// ---------------- GEMM1 + fused alpha1: h1 = x@W1; as1/ad1 per (row,head) ----------------
__global__ __launch_bounds__(256) void gemm1_kernel(const float* __restrict__ A, const float* __restrict__ B,
                                                    const float* __restrict__ a_src, const float* __restrict__ a_dst,
                                                    float* __restrict__ C, float* __restrict__ as1,
                                                    float* __restrict__ ad1, int M) {
    __shared__ float As[16][128];
    __shared__ float Bs[16][128];
    int t = threadIdx.x;
    int tx = t & 15, ty = t >> 4;
    int row0 = blockIdx.x * 128, col0 = blockIdx.y * 128;
    float acc[8][8] = {};
    for (int k0 = 0; k0 < 128; k0 += 16) {
        #pragma unroll
        for (int u = 0; u < 2; u++) {
            int idx = t * 2 + u;
            int r = idx >> 2, kc = idx & 3;
            int grow = row0 + r; if (grow >= M) grow = M - 1;
            float4 av = *(const float4*)&A[(size_t)grow * 128 + k0 + kc * 4];
            As[kc * 4 + 0][r] = av.x; As[kc * 4 + 1][r] = av.y;
            As[kc * 4 + 2][r] = av.z; As[kc * 4 + 3][r] = av.w;
        }
        #pragma unroll
        for (int u = 0; u < 2; u++) {
            int idx = t * 2 + u;
            int kk = idx >> 5, cc = idx & 31;
            *(float4*)&Bs[kk][cc * 4] = *(const float4*)&B[(size_t)(k0 + kk) * 256 + col0 + cc * 4];
        }
        __syncthreads();
        #pragma unroll
        for (int k = 0; k < 16; k++) {
            float a[8], b[8];
            *(float4*)&a[0] = *(float4*)&As[k][ty * 8];
            *(float4*)&a[4] = *(float4*)&As[k][ty * 8 + 4];
            *(float4*)&b[0] = *(float4*)&Bs[k][tx * 8];
            *(float4*)&b[4] = *(float4*)&Bs[k][tx * 8 + 4];
            #pragma unroll
            for (int i = 0; i < 8; i++)
                #pragma unroll
                for (int j = 0; j < 8; j++)
                    acc[i][j] += a[i] * b[j];
        }
        __syncthreads();
    }
    // C stores
    #pragma unroll
    for (int i = 0; i < 8; i++) {
        int r = row0 + ty * 8 + i;
        if (r < M) {
            *(float4*)&C[(size_t)r * 256 + col0 + tx * 8]     = make_float4(acc[i][0], acc[i][1], acc[i][2], acc[i][3]);
            *(float4*)&C[(size_t)r * 256 + col0 + tx * 8 + 4] = make_float4(acc[i][4], acc[i][5], acc[i][6], acc[i][7]);
        }
    }
    // fused alpha: this thread's 8 cols lie inside head hh (32-col groups)
    float avs[8], avd[8];
    #pragma unroll
    for (int j = 0; j < 8; j++) { avs[j] = a_src[col0 + tx * 8 + j]; avd[j] = a_dst[col0 + tx * 8 + j]; }
    int hh = (col0 >> 5) + (tx >> 2);
    #pragma unroll
    for (int i = 0; i < 8; i++) {
        float ps = 0.f, pd = 0.f;
        #pragma unroll
        for (int j = 0; j < 8; j++) { ps += acc[i][j] * avs[j]; pd += acc[i][j] * avd[j]; }
        ps += __shfl_xor(ps, 1); ps += __shfl_xor(ps, 2);
        pd += __shfl_xor(pd, 1); pd += __shfl_xor(pd, 2);
        int r = row0 + ty * 8 + i;
        if ((tx & 3) == 0 && r < M) { as1[r * 8 + hh] = ps; ad1[r * 8 + hh] = pd; }
    }
}

// ---------------- agg1 v4: wave/node, 16 gathers in flight ----------------
__global__ __launch_bounds__(256) void agg1_kernel(const float* __restrict__ h1, const float* __restrict__ asrc,
                                                   const float* __restrict__ adst, const int* __restrict__ row_start,
                                                   const int* __restrict__ srcs, const float* __restrict__ b1,
                                                   float* __restrict__ h1p, int N) {
    int node = blockIdx.x * 4 + (threadIdx.x >> 6);
    if (node >= N) return;
    int lane = threadIdx.x & 63;
    int h = lane >> 3, e8 = lane & 7;
    float adn = adst[node * 8 + h];
    int rs = row_start[node], re = row_start[node + 1];
    float4 acc = make_float4(0.f, 0.f, 0.f, 0.f);
    float den = 0.f;
    int o4 = lane * 4;
    for (int base = rs; base < re; base += 64) {
        int cnt = re - base; if (cnt > 64) cnt = 64;
        int sv = srcs[base + (lane < cnt ? lane : 0)];
        int g = 0;
        for (; g + 16 <= cnt; g += 16) {
            int ssA = __shfl(sv, g + e8);
            int ssB = __shfl(sv, g + 8 + e8);
            float wA = __expf(lrelu(asrc[ssA * 8 + h] + adn));
            float wB = __expf(lrelu(asrc[ssB * 8 + h] + adn));
            float4 v[16];
            #pragma unroll
            for (int q = 0; q < 16; q++) {
                int s = __shfl(sv, g + q);
                v[q] = *(const float4*)&h1[(size_t)s * 256 + o4];
            }
            #pragma unroll
            for (int q = 0; q < 8; q++) {
                float w = __shfl(wA, (h << 3) | q);
                acc.x += w * v[q].x; acc.y += w * v[q].y; acc.z += w * v[q].z; acc.w += w * v[q].w;
                den += w;
            }
            #pragma unroll
            for (int q = 8; q < 16; q++) {
                float w = __shfl(wB, (h << 3) | (q - 8));
                acc.x += w * v[q].x; acc.y += w * v[q].y; acc.z += w * v[q].z; acc.w += w * v[q].w;
                den += w;
            }
        }
        if (g + 8 <= cnt) {
            int ss = __shfl(sv, g + e8);
            float wp = __expf(lrelu(asrc[ss * 8 + h] + adn));
            float4 v[8];
            #pragma unroll
            for (int q = 0; q < 8; q++) {
                int s = __shfl(sv, g + q);
                v[q] = *(const float4*)&h1[(size_t)s * 256 + o4];
            }
            #pragma unroll
            for (int q = 0; q < 8; q++) {
                float w = __shfl(wp, (h << 3) | q);
                acc.x += w * v[q].x; acc.y += w * v[q].y; acc.z += w * v[q].z; acc.w += w * v[q].w;
                den += w;
            }
            g += 8;
        }
        if (g < cnt) {
            int ep = g + e8;
            int epc = ep < cnt - 1 ? ep : cnt - 1;
            int ss = __shfl(sv, epc);
            float wp = (ep < cnt) ? __expf(lrelu(asrc[ss * 8 + h] + adn)) : 0.f;
            #pragma unroll
            for (int q = 0; q < 8; q++) {
                if (g + q < cnt) {   // wave-uniform
                    int s = __shfl(sv, g + q);
                    float w = __shfl(wp, (h << 3) | q);
                    const float4 vv = *(const float4*)&h1[(size_t)s * 256 + o4];
                    acc.x += w * vv.x; acc.y += w * vv.y; acc.z += w * vv.z; acc.w += w * vv.w;
                    den += w;
                }
            }
        }
    }
    float inv = 1.f / den;
    float4 r;
    r.x = elu1(acc.x * inv + b1[o4 + 0]);
    r.y = elu1(acc.y * inv + b1[o4 + 1]);
    r.z = elu1(acc.z * inv + b1[o4 + 2]);
    r.w = elu1(acc.w * inv + b1[o4 + 3]);
    *(float4*)&h1p[(size_t)node * 256 + o4] = r;
}

// ---------------- GEMM2 + alpha2: register-resident W2, broadcast X reads ----------------
__global__ __launch_bounds__(256) void gemm2_kernel(const float* __restrict__ X, const float* __restrict__ W2,
                                                    const float* __restrict__ a_src2, const float* __restrict__ a_dst2,
                                                    float* __restrict__ h2, float* __restrict__ asrc2,
                                                    float* __restrict__ adst2, int N) {
    int lane = threadIdx.x & 63;
    int c = lane & 15, kq = lane >> 4;
    int wid = blockIdx.x * (blockDim.x >> 6) + (threadIdx.x >> 6);
    int nwaves = gridDim.x * (blockDim.x >> 6);
    float w2r[64];
    #pragma unroll
    for (int i = 0; i < 64; i++) w2r[i] = W2[(kq * 64 + i) * 16 + c];
    float as_c = a_src2[c], ad_c = a_dst2[c];
    for (int n = wid; n < N; n += nwaves) {
        const float* xp = &X[(size_t)n * 256 + kq * 64];
        float acc = 0.f;
        #pragma unroll
        for (int i4 = 0; i4 < 16; i4++) {
            float4 xv = *(const float4*)&xp[i4 * 4];
            acc += xv.x * w2r[i4 * 4] + xv.y * w2r[i4 * 4 + 1] + xv.z * w2r[i4 * 4 + 2] + xv.w * w2r[i4 * 4 + 3];
        }
        acc += __shfl_xor(acc, 16);
        acc += __shfl_xor(acc, 32);
        float s1 = acc * as_c, s2 = acc * ad_c;
        #pragma unroll
        for (int off = 1; off < 16; off <<= 1) { s1 += __shfl_xor(s1, off); s2 += __shfl_xor(s2, off); }
        if (kq == 0) h2[n * 16 + c] = acc;
        if (lane == 0) { asrc2[n] = s1; adst2[n] = s2; }
    }
}

// ---------------- agg2 + fused gemm3: h4[node] = (elu(att_agg + b2)) @ W3 ----------------
__global__ __launch_bounds__(256) void agg2_kernel(const float* __restrict__ h2, const float* __restrict__ asrc2,
                                                   const float* __restrict__ adst2, const int* __restrict__ row_start,
                                                   const int* __restrict__ srcs, const float* __restrict__ b2,
                                                   const float* __restrict__ W3, float* __restrict__ h4, int N) {
    int node = blockIdx.x * 4 + (threadIdx.x >> 6);
    if (node >= N) return;
    int lane = threadIdx.x & 63;
    int q = lane >> 4, c = lane & 15;
    float adn = adst2[node];
    int rs = row_start[node], re = row_start[node + 1];
    float acc = 0.f, den = 0.f;
    for (int base = rs; base < re; base += 64) {
        int cnt = re - base; if (cnt > 64) cnt = 64;
        int sv = 0; float wv = 0.f;
        if (lane < cnt) { sv = srcs[base + lane]; wv = __expf(lrelu(asrc2[sv] + adn)); }
        int nit = (cnt + 3) >> 2;
        for (int it = 0; it < nit; it++) {
            int j = it * 4 + q;
            int s = __shfl(sv, j);
            float w = __shfl(wv, j);     // 0 for j >= cnt
            float v = h2[s * 16 + c];
            acc += w * v; den += w;
        }
    }
    acc += __shfl_xor(acc, 16); acc += __shfl_xor(acc, 32);
    den += __shfl_xor(den, 16); den += __shfl_xor(den, 32);
    float h3v = elu1(acc / den + b2[c]);     // identical across q groups
    // fused 16x16 gemm3: h4[c'] = sum_cs h3[cs] * W3[cs][c']
    float h4v = 0.f;
    #pragma unroll
    for (int cs = 0; cs < 16; cs++) {
        float hv = __shfl(h3v, cs);          // lane cs holds column cs
        h4v += hv * W3[cs * 16 + c];
    }
    if (q == 0) h4[node * 16 + c] = h4v;
}

// ---------------- agg3 (GCN): wave/node, 4 edges in flight ----------------
__global__ __launch_bounds__(256) void agg3_kernel(const float* __restrict__ h4, const float* __restrict__ dinv,
                                                   const int* __restrict__ row_start, const int* __restrict__ srcs,
                                                   const float* __restrict__ b3, float* __restrict__ out, int N) {
    int node = blockIdx.x * 4 + (threadIdx.x >> 6);
    if (node >= N) return;
    int lane = threadIdx.x & 63;
    int q = lane >> 4, c = lane & 15;
    int rs = row_start[node], re = row_start[node + 1];
    float acc = 0.f;
    for (int base = rs; base < re; base += 64) {
        int cnt = re - base; if (cnt > 64) cnt = 64;
        int sv = 0; float wv = 0.f;
        if (lane < cnt) { sv = srcs[base + lane]; wv = dinv[sv]; }
        int nit = (cnt + 3) >> 2;
        for (int it = 0; it < nit; it++) {
            int j = it * 4 + q;
            int s = __shfl(sv, j);
            float w = __shfl(wv, j);
            float v = h4[s * 16 + c];
            acc += w * v;
        }
    }
    acc += __shfl_xor(acc, 16); acc += __shfl_xor(acc, 32);
    if (q == 0) out[node * 16 + c] = acc * dinv[node] + b3[c];
}

extern "C" void kernel_launch(void* const* d_in, const int* in_sizes, int n_in,
                              void* d_out, int out_size, void* d_ws, size_t ws_size,
                              hipStream_t stream) {
    const float* x      = (const float*)d_in[0];
    const int*   ei     = (const int*)d_in[1];
    const float* W1     = (const float*)d_in[2];
    const float* a_src1 = (const float*)d_in[3];
    const float* a_dst1 = (const float*)d_in[4];
    const float* b1     = (const float*)d_in[5];
    const float* W2     = (const float*)d_in[6];
    const float* a_src2 = (const float*)d_in[7];
    const float* a_dst2 = (const float*)d_in[8];
    const float* b2     = (const float*)d_in[9];
    const float* W3     = (const float*)d_in[10];
    const float* b3     = (const float*)d_in[11];
    float* out = (float*)d_out;

    const int N  = in_sizes[0] / 128;   // 50000
    const int E  = in_sizes[1] / 2;     // 800000
    const int E2 = E + N;
    const int NB = (N + 255) / 256;

    char* p = (char*)d_ws;
    auto alloc = [&](size_t bytes) -> void* {
        void* r = (void*)p;
        p += (bytes + 255) & ~(size_t)255;
        return r;
    };
    int*   counts = (int*)alloc((size_t)N * 4);
    int*   rowst  = (int*)alloc((size_t)(N + 1) * 4);
    int*   fillc  = (int*)alloc((size_t)N * 4);
    int*   srcs   = (int*)alloc((size_t)E2 * 4);
    int*   bsum   = (int*)alloc((size_t)NB * 4);
    float* h1     = (float*)alloc((size_t)N * 256 * 4);
    float* h1p    = (float*)alloc((size_t)N * 256 * 4);
    float* as1    = (float*)alloc((size_t)N * 8 * 4);
    float* ad1    = (float*)alloc((size_t)N * 8 * 4);
    float* h2     = (float*)alloc((size_t)N * 16 * 4);
    float* as2    = (float*)alloc((size_t)N * 4);
    float* ad2    = (float*)alloc((size_t)N * 4);
    float* h4     = (float*)alloc((size_t)N * 16 * 4);
    float* dinv   = (float*)alloc((size_t)N * 4);

    hipMemsetAsync(counts, 0, (size_t)N * 4, stream);

    count_kernel<<<(E2 + 255) / 256, 256, 0, stream>>>(ei, counts, E, E2);
    scanA_kernel<<<NB, 256, 0, stream>>>(counts, bsum, N);
    scanB_kernel<<<1, 256, 0, stream>>>(bsum, NB);
    scanC_kernel<<<NB, 256, 0, stream>>>(counts, bsum, rowst, fillc, dinv, N);
    fill_kernel<<<(E2 + 255) / 256, 256, 0, stream>>>(ei, fillc, srcs, E, E2);

    gemm1_kernel<<<dim3((N + 127) / 128, 2), 256, 0, stream>>>(x, W1, a_src1, a_dst1, h1, as1, ad1, N);
    agg1_kernel<<<(N + 3) / 4, 256, 0, stream>>>(h1, as1, ad1, rowst, srcs, b1, h1p, N);

    gemm2_kernel<<<1024, 256, 0, stream>>>(h1p, W2, a_src2, a_dst2, h2, as2, ad2, N);
    agg2_kernel<<<(N + 3) / 4, 256, 0, stream>>>(h2, as2, ad2, rowst, srcs, b2, W3, h4, N);

    agg3_kernel<<<(N + 3) / 4, 256, 0, stream>>>(h4, dinv, rowst, srcs, b3, out, N);
}

// Round 6
// 395.032 us; speedup vs baseline: 1.8867x; 1.1275x over previous
//
#include <hip/hip_runtime.h>
#include <hip/hip_bf16.h>
#include <math.h>

#define NEG_SLOPE 0.2f

typedef float f32x4 __attribute__((ext_vector_type(4)));

static __device__ __forceinline__ float lrelu(float x) { return x > 0.f ? x : NEG_SLOPE * x; }
static __device__ __forceinline__ float elu1(float x)  { return x > 0.f ? x : (expf(x) - 1.f); }

static __device__ __forceinline__ unsigned short f2bf(float x) {
    __hip_bfloat16 h = __float2bfloat16(x);
    return *reinterpret_cast<unsigned short*>(&h);
}
static __device__ __forceinline__ unsigned int pack2bf(float a, float b) {
    return (unsigned int)f2bf(a) | ((unsigned int)f2bf(b) << 16);
}
static __device__ __forceinline__ float bflo(unsigned int u) { return __uint_as_float(u << 16); }
static __device__ __forceinline__ float bfhi(unsigned int u) { return __uint_as_float(u & 0xFFFF0000u); }

// ---------------- CSR build (by dst), reused for all 3 layers ----------------
__global__ void count_kernel(const int* __restrict__ ei, int* __restrict__ counts, int E, int E2) {
    int i = blockIdx.x * blockDim.x + threadIdx.x;
    if (i >= E2) return;
    int dst = (i < E) ? ei[E + i] : (i - E);
    atomicAdd(&counts[dst], 1);
}

// phase A: per-256-tile sums
__global__ __launch_bounds__(256) void scanA_kernel(const int* __restrict__ counts, int* __restrict__ blocksum, int N) {
    __shared__ int red[256];
    int t = threadIdx.x;
    int i = blockIdx.x * 256 + t;
    int v = (i < N) ? counts[i] : 0;
    red[t] = v; __syncthreads();
    for (int off = 128; off >= 1; off >>= 1) {
        if (t < off) red[t] += red[t + off];
        __syncthreads();
    }
    if (t == 0) blocksum[blockIdx.x] = red[0];
}

// phase B: exclusive scan of block sums (single block, chunked)
__global__ __launch_bounds__(256) void scanB_kernel(int* __restrict__ bs, int NB) {
    __shared__ int sm[256];
    int t = threadIdx.x;
    int carry = 0;
    for (int b0 = 0; b0 < NB; b0 += 256) {
        int v = (b0 + t < NB) ? bs[b0 + t] : 0;
        sm[t] = v; __syncthreads();
        for (int off = 1; off < 256; off <<= 1) {
            int u = (t >= off) ? sm[t - off] : 0;
            __syncthreads();
            sm[t] += u;
            __syncthreads();
        }
        if (b0 + t < NB) bs[b0 + t] = carry + sm[t] - v;
        int tot = sm[255];
        __syncthreads();
        carry += tot;
    }
}

// phase C: row_start + fillc(start positions) + dinv
__global__ __launch_bounds__(256) void scanC_kernel(const int* __restrict__ counts, const int* __restrict__ blocksum,
                                                    int* __restrict__ row_start, int* __restrict__ fillc,
                                                    float* __restrict__ dinv, int N) {
    __shared__ int sm[256];
    int t = threadIdx.x;
    int i = blockIdx.x * 256 + t;
    int v = (i < N) ? counts[i] : 0;
    sm[t] = v; __syncthreads();
    for (int off = 1; off < 256; off <<= 1) {
        int u = (t >= off) ? sm[t - off] : 0;
        __syncthreads();
        sm[t] += u;
        __syncthreads();
    }
    if (i < N) {
        int rsv = blocksum[blockIdx.x] + sm[t] - v;
        row_start[i] = rsv;
        fillc[i] = rsv;
        dinv[i] = rsqrtf((float)v);   // v >= 1 due to self-loop
    }
    if (i == N - 1) row_start[N] = blocksum[blockIdx.x] + sm[t];
}

// scatter src ids into CSR slots (fillc pre-seeded with row starts)
__global__ void fill_kernel(const int* __restrict__ ei, int* __restrict__ fillc,
                            int* __restrict__ srcs, int E, int E2) {
    int i = blockIdx.x * blockDim.x + threadIdx.x;
    if (i >= E2) return;
    int src, dst;
    if (i < E) { src = ei[i]; dst = ei[E + i]; }
    else       { src = i - E; dst = i - E; }
    int pos = atomicAdd(&fillc[dst], 1);
    srcs[pos] = src;
}

// ---------------- GEMM1 + fused alpha1: h1(bf16) = x@W1; as1/ad1 per (row,head) ----------------
__global__ __launch_bounds__(256) void gemm1_kernel(const float* __restrict__ A, const float* __restrict__ B,
                                                    const float* __restrict__ a_src, const float* __restrict__ a_dst,
                                                    unsigned short* __restrict__ Cb, float* __restrict__ as1,
                                                    float* __restrict__ ad1, int M) {
    __shared__ float As[16][128];
    __shared__ float Bs[16][128];
    int t = threadIdx.x;
    int tx = t & 15, ty = t >> 4;
    int row0 = blockIdx.x * 128, col0 = blockIdx.y * 128;
    float acc[8][8] = {};
    for (int k0 = 0; k0 < 128; k0 += 16) {
        #pragma unroll
        for (int u = 0; u < 2; u++) {
            int idx = t * 2 + u;
            int r = idx >> 2, kc = idx & 3;
            int grow = row0 + r; if (grow >= M) grow = M - 1;
            float4 av = *(const float4*)&A[(size_t)grow * 128 + k0 + kc * 4];
            As[kc * 4 + 0][r] = av.x; As[kc * 4 + 1][r] = av.y;
            As[kc * 4 + 2][r] = av.z; As[kc * 4 + 3][r] = av.w;
        }
        #pragma unroll
        for (int u = 0; u < 2; u++) {
            int idx = t * 2 + u;
            int kk = idx >> 5, cc = idx & 31;
            *(float4*)&Bs[kk][cc * 4] = *(const float4*)&B[(size_t)(k0 + kk) * 256 + col0 + cc * 4];
        }
        __syncthreads();
        #pragma unroll
        for (int k = 0; k < 16; k++) {
            float a[8], b[8];
            *(float4*)&a[0] = *(float4*)&As[k][ty * 8];
            *(float4*)&a[4] = *(float4*)&As[k][ty * 8 + 4];
            *(float4*)&b[0] = *(float4*)&Bs[k][tx * 8];
            *(float4*)&b[4] = *(float4*)&Bs[k][tx * 8 + 4];
            #pragma unroll
            for (int i = 0; i < 8; i++)
                #pragma unroll
                for (int j = 0; j < 8; j++)
                    acc[i][j] += a[i] * b[j];
        }
        __syncthreads();
    }
    // bf16 C stores (h1 gather table)
    #pragma unroll
    for (int i = 0; i < 8; i++) {
        int r = row0 + ty * 8 + i;
        if (r < M) {
            uint4 pk;
            pk.x = pack2bf(acc[i][0], acc[i][1]);
            pk.y = pack2bf(acc[i][2], acc[i][3]);
            pk.z = pack2bf(acc[i][4], acc[i][5]);
            pk.w = pack2bf(acc[i][6], acc[i][7]);
            *(uint4*)&Cb[(size_t)r * 256 + col0 + tx * 8] = pk;
        }
    }
    // fused alpha (fp32 accs, exact): this thread's 8 cols lie inside head hh
    float avs[8], avd[8];
    #pragma unroll
    for (int j = 0; j < 8; j++) { avs[j] = a_src[col0 + tx * 8 + j]; avd[j] = a_dst[col0 + tx * 8 + j]; }
    int hh = (col0 >> 5) + (tx >> 2);
    #pragma unroll
    for (int i = 0; i < 8; i++) {
        float ps = 0.f, pd = 0.f;
        #pragma unroll
        for (int j = 0; j < 8; j++) { ps += acc[i][j] * avs[j]; pd += acc[i][j] * avd[j]; }
        ps += __shfl_xor(ps, 1); ps += __shfl_xor(ps, 2);
        pd += __shfl_xor(pd, 1); pd += __shfl_xor(pd, 2);
        int r = row0 + ty * 8 + i;
        if ((tx & 3) == 0 && r < M) { as1[r * 8 + hh] = ps; ad1[r * 8 + hh] = pd; }
    }
}

// ---------------- agg1 v5: wave/node, bf16 gathers (8B/lane), 16 in flight ----------------
__global__ __launch_bounds__(256) void agg1_kernel(const unsigned short* __restrict__ h1b, const float* __restrict__ asrc,
                                                   const float* __restrict__ adst, const int* __restrict__ row_start,
                                                   const int* __restrict__ srcs, const float* __restrict__ b1,
                                                   float* __restrict__ h1p, int N) {
    int node = blockIdx.x * 4 + (threadIdx.x >> 6);
    if (node >= N) return;
    int lane = threadIdx.x & 63;
    int h = lane >> 3, e8 = lane & 7;
    float adn = adst[node * 8 + h];
    int rs = row_start[node], re = row_start[node + 1];
    float4 acc = make_float4(0.f, 0.f, 0.f, 0.f);
    float den = 0.f;
    int o4 = lane * 4;
    for (int base = rs; base < re; base += 64) {
        int cnt = re - base; if (cnt > 64) cnt = 64;
        int sv = __builtin_nontemporal_load(&srcs[base + (lane < cnt ? lane : 0)]);
        int g = 0;
        for (; g + 16 <= cnt; g += 16) {
            int ssA = __shfl(sv, g + e8);
            int ssB = __shfl(sv, g + 8 + e8);
            float wA = __expf(lrelu(asrc[ssA * 8 + h] + adn));
            float wB = __expf(lrelu(asrc[ssB * 8 + h] + adn));
            uint2 v[16];
            #pragma unroll
            for (int q = 0; q < 16; q++) {
                int s = __shfl(sv, g + q);
                v[q] = *(const uint2*)&h1b[(size_t)s * 256 + o4];
            }
            #pragma unroll
            for (int q = 0; q < 8; q++) {
                float w = __shfl(wA, (h << 3) | q);
                acc.x += w * bflo(v[q].x); acc.y += w * bfhi(v[q].x);
                acc.z += w * bflo(v[q].y); acc.w += w * bfhi(v[q].y);
                den += w;
            }
            #pragma unroll
            for (int q = 8; q < 16; q++) {
                float w = __shfl(wB, (h << 3) | (q - 8));
                acc.x += w * bflo(v[q].x); acc.y += w * bfhi(v[q].x);
                acc.z += w * bflo(v[q].y); acc.w += w * bfhi(v[q].y);
                den += w;
            }
        }
        if (g + 8 <= cnt) {
            int ss = __shfl(sv, g + e8);
            float wp = __expf(lrelu(asrc[ss * 8 + h] + adn));
            uint2 v[8];
            #pragma unroll
            for (int q = 0; q < 8; q++) {
                int s = __shfl(sv, g + q);
                v[q] = *(const uint2*)&h1b[(size_t)s * 256 + o4];
            }
            #pragma unroll
            for (int q = 0; q < 8; q++) {
                float w = __shfl(wp, (h << 3) | q);
                acc.x += w * bflo(v[q].x); acc.y += w * bfhi(v[q].x);
                acc.z += w * bflo(v[q].y); acc.w += w * bfhi(v[q].y);
                den += w;
            }
            g += 8;
        }
        if (g < cnt) {
            int ep = g + e8;
            int epc = ep < cnt - 1 ? ep : cnt - 1;
            int ss = __shfl(sv, epc);
            float wp = (ep < cnt) ? __expf(lrelu(asrc[ss * 8 + h] + adn)) : 0.f;
            #pragma unroll
            for (int q = 0; q < 8; q++) {
                if (g + q < cnt) {   // wave-uniform
                    int s = __shfl(sv, g + q);
                    float w = __shfl(wp, (h << 3) | q);
                    uint2 vv = *(const uint2*)&h1b[(size_t)s * 256 + o4];
                    acc.x += w * bflo(vv.x); acc.y += w * bfhi(vv.x);
                    acc.z += w * bflo(vv.y); acc.w += w * bfhi(vv.y);
                    den += w;
                }
            }
        }
    }
    float inv = 1.f / den;
    f32x4 r;
    r.x = elu1(acc.x * inv + b1[o4 + 0]);
    r.y = elu1(acc.y * inv + b1[o4 + 1]);
    r.z = elu1(acc.z * inv + b1[o4 + 2]);
    r.w = elu1(acc.w * inv + b1[o4 + 3]);
    __builtin_nontemporal_store(r, (f32x4*)&h1p[(size_t)node * 256 + o4]);
}

// ---------------- GEMM2 + alpha2: register-resident W2, broadcast X reads ----------------
__global__ __launch_bounds__(256) void gemm2_kernel(const float* __restrict__ X, const float* __restrict__ W2,
                                                    const float* __restrict__ a_src2, const float* __restrict__ a_dst2,
                                                    float* __restrict__ h2, float* __restrict__ asrc2,
                                                    float* __restrict__ adst2, int N) {
    int lane = threadIdx.x & 63;
    int c = lane & 15, kq = lane >> 4;
    int wid = blockIdx.x * (blockDim.x >> 6) + (threadIdx.x >> 6);
    int nwaves = gridDim.x * (blockDim.x >> 6);
    float w2r[64];
    #pragma unroll
    for (int i = 0; i < 64; i++) w2r[i] = W2[(kq * 64 + i) * 16 + c];
    float as_c = a_src2[c], ad_c = a_dst2[c];
    for (int n = wid; n < N; n += nwaves) {
        const float* xp = &X[(size_t)n * 256 + kq * 64];
        float acc = 0.f;
        #pragma unroll
        for (int i4 = 0; i4 < 16; i4++) {
            float4 xv = *(const float4*)&xp[i4 * 4];
            acc += xv.x * w2r[i4 * 4] + xv.y * w2r[i4 * 4 + 1] + xv.z * w2r[i4 * 4 + 2] + xv.w * w2r[i4 * 4 + 3];
        }
        acc += __shfl_xor(acc, 16);
        acc += __shfl_xor(acc, 32);
        float s1 = acc * as_c, s2 = acc * ad_c;
        #pragma unroll
        for (int off = 1; off < 16; off <<= 1) { s1 += __shfl_xor(s1, off); s2 += __shfl_xor(s2, off); }
        if (kq == 0) h2[n * 16 + c] = acc;
        if (lane == 0) { asrc2[n] = s1; adst2[n] = s2; }
    }
}

// ---------------- agg2 + fused gemm3: h4[node] = (elu(att_agg + b2)) @ W3 ----------------
__global__ __launch_bounds__(256) void agg2_kernel(const float* __restrict__ h2, const float* __restrict__ asrc2,
                                                   const float* __restrict__ adst2, const int* __restrict__ row_start,
                                                   const int* __restrict__ srcs, const float* __restrict__ b2,
                                                   const float* __restrict__ W3, float* __restrict__ h4, int N) {
    int node = blockIdx.x * 4 + (threadIdx.x >> 6);
    if (node >= N) return;
    int lane = threadIdx.x & 63;
    int q = lane >> 4, c = lane & 15;
    float adn = adst2[node];
    int rs = row_start[node], re = row_start[node + 1];
    float acc = 0.f, den = 0.f;
    for (int base = rs; base < re; base += 64) {
        int cnt = re - base; if (cnt > 64) cnt = 64;
        int sv = 0; float wv = 0.f;
        if (lane < cnt) { sv = __builtin_nontemporal_load(&srcs[base + lane]); wv = __expf(lrelu(asrc2[sv] + adn)); }
        int nit = (cnt + 3) >> 2;
        for (int it = 0; it < nit; it++) {
            int j = it * 4 + q;
            int s = __shfl(sv, j);
            float w = __shfl(wv, j);     // 0 for j >= cnt
            float v = h2[s * 16 + c];
            acc += w * v; den += w;
        }
    }
    acc += __shfl_xor(acc, 16); acc += __shfl_xor(acc, 32);
    den += __shfl_xor(den, 16); den += __shfl_xor(den, 32);
    float h3v = elu1(acc / den + b2[c]);     // identical across q groups
    float h4v = 0.f;
    #pragma unroll
    for (int cs = 0; cs < 16; cs++) {
        float hv = __shfl(h3v, cs);          // lane cs holds column cs
        h4v += hv * W3[cs * 16 + c];
    }
    if (q == 0) h4[node * 16 + c] = h4v;
}

// ---------------- agg3 (GCN): wave/node, 4 edges in flight ----------------
__global__ __launch_bounds__(256) void agg3_kernel(const float* __restrict__ h4, const float* __restrict__ dinv,
                                                   const int* __restrict__ row_start, const int* __restrict__ srcs,
                                                   const float* __restrict__ b3, float* __restrict__ out, int N) {
    int node = blockIdx.x * 4 + (threadIdx.x >> 6);
    if (node >= N) return;
    int lane = threadIdx.x & 63;
    int q = lane >> 4, c = lane & 15;
    int rs = row_start[node], re = row_start[node + 1];
    float acc = 0.f;
    for (int base = rs; base < re; base += 64) {
        int cnt = re - base; if (cnt > 64) cnt = 64;
        int sv = 0; float wv = 0.f;
        if (lane < cnt) { sv = __builtin_nontemporal_load(&srcs[base + lane]); wv = dinv[sv]; }
        int nit = (cnt + 3) >> 2;
        for (int it = 0; it < nit; it++) {
            int j = it * 4 + q;
            int s = __shfl(sv, j);
            float w = __shfl(wv, j);
            float v = h4[s * 16 + c];
            acc += w * v;
        }
    }
    acc += __shfl_xor(acc, 16); acc += __shfl_xor(acc, 32);
    if (q == 0) out[node * 16 + c] = acc * dinv[node] + b3[c];
}

extern "C" void kernel_launch(void* const* d_in, const int* in_sizes, int n_in,
                              void* d_out, int out_size, void* d_ws, size_t ws_size,
                              hipStream_t stream) {
    const float* x      = (const float*)d_in[0];
    const int*   ei     = (const int*)d_in[1];
    const float* W1     = (const float*)d_in[2];
    const float* a_src1 = (const float*)d_in[3];
    const float* a_dst1 = (const float*)d_in[4];
    const float* b1     = (const float*)d_in[5];
    const float* W2     = (const float*)d_in[6];
    const float* a_src2 = (const float*)d_in[7];
    const float* a_dst2 = (const float*)d_in[8];
    const float* b2     = (const float*)d_in[9];
    const float* W3     = (const float*)d_in[10];
    const float* b3     = (const float*)d_in[11];
    float* out = (float*)d_out;

    const int N  = in_sizes[0] / 128;   // 50000
    const int E  = in_sizes[1] / 2;     // 800000
    const int E2 = E + N;
    const int NB = (N + 255) / 256;

    char* p = (char*)d_ws;
    auto alloc = [&](size_t bytes) -> void* {
        void* r = (void*)p;
        p += (bytes + 255) & ~(size_t)255;
        return r;
    };
    int*   counts = (int*)alloc((size_t)N * 4);
    int*   rowst  = (int*)alloc((size_t)(N + 1) * 4);
    int*   fillc  = (int*)alloc((size_t)N * 4);
    int*   srcs   = (int*)alloc((size_t)E2 * 4);
    int*   bsum   = (int*)alloc((size_t)NB * 4);
    unsigned short* h1b = (unsigned short*)alloc((size_t)N * 256 * 2);
    float* h1p    = (float*)alloc((size_t)N * 256 * 4);
    float* as1    = (float*)alloc((size_t)N * 8 * 4);
    float* ad1    = (float*)alloc((size_t)N * 8 * 4);
    float* h2     = (float*)alloc((size_t)N * 16 * 4);
    float* as2    = (float*)alloc((size_t)N * 4);
    float* ad2    = (float*)alloc((size_t)N * 4);
    float* h4     = (float*)alloc((size_t)N * 16 * 4);
    float* dinv   = (float*)alloc((size_t)N * 4);

    (void)hipMemsetAsync(counts, 0, (size_t)N * 4, stream);

    count_kernel<<<(E2 + 255) / 256, 256, 0, stream>>>(ei, counts, E, E2);
    scanA_kernel<<<NB, 256, 0, stream>>>(counts, bsum, N);
    scanB_kernel<<<1, 256, 0, stream>>>(bsum, NB);
    scanC_kernel<<<NB, 256, 0, stream>>>(counts, bsum, rowst, fillc, dinv, N);
    fill_kernel<<<(E2 + 255) / 256, 256, 0, stream>>>(ei, fillc, srcs, E, E2);

    gemm1_kernel<<<dim3((N + 127) / 128, 2), 256, 0, stream>>>(x, W1, a_src1, a_dst1, h1b, as1, ad1, N);
    agg1_kernel<<<(N + 3) / 4, 256, 0, stream>>>(h1b, as1, ad1, rowst, srcs, b1, h1p, N);

    gemm2_kernel<<<1024, 256, 0, stream>>>(h1p, W2, a_src2, a_dst2, h2, as2, ad2, N);
    agg2_kernel<<<(N + 3) / 4, 256, 0, stream>>>(h2, as2, ad2, rowst, srcs, b2, W3, h4, N);

    agg3_kernel<<<(N + 3) / 4, 256, 0, stream>>>(h4, dinv, rowst, srcs, b3, out, N);
}

// Round 7
// 377.106 us; speedup vs baseline: 1.9764x; 1.0475x over previous
//
#include <hip/hip_runtime.h>
#include <hip/hip_bf16.h>
#include <math.h>

#define NEG_SLOPE 0.2f

typedef float f32x4 __attribute__((ext_vector_type(4)));
typedef short bf16x8 __attribute__((ext_vector_type(8)));

static __device__ __forceinline__ float lrelu(float x) { return x > 0.f ? x : NEG_SLOPE * x; }
static __device__ __forceinline__ float elu1(float x)  { return x > 0.f ? x : (expf(x) - 1.f); }

static __device__ __forceinline__ unsigned short f2bf(float x) {
    __hip_bfloat16 h = __float2bfloat16(x);
    return *reinterpret_cast<unsigned short*>(&h);
}
static __device__ __forceinline__ unsigned int pack2bf(float a, float b) {
    return (unsigned int)f2bf(a) | ((unsigned int)f2bf(b) << 16);
}
static __device__ __forceinline__ float bflo(unsigned int u) { return __uint_as_float(u << 16); }
static __device__ __forceinline__ float bfhi(unsigned int u) { return __uint_as_float(u & 0xFFFF0000u); }

// ---------------- CSR build (by dst), reused for all 3 layers ----------------
__global__ void count_kernel(const int* __restrict__ ei, int* __restrict__ counts, int E, int E2) {
    int i = blockIdx.x * blockDim.x + threadIdx.x;
    if (i >= E2) return;
    int dst = (i < E) ? ei[E + i] : (i - E);
    atomicAdd(&counts[dst], 1);
}

__global__ __launch_bounds__(256) void scanA_kernel(const int* __restrict__ counts, int* __restrict__ blocksum, int N) {
    __shared__ int red[256];
    int t = threadIdx.x;
    int i = blockIdx.x * 256 + t;
    int v = (i < N) ? counts[i] : 0;
    red[t] = v; __syncthreads();
    for (int off = 128; off >= 1; off >>= 1) {
        if (t < off) red[t] += red[t + off];
        __syncthreads();
    }
    if (t == 0) blocksum[blockIdx.x] = red[0];
}

__global__ __launch_bounds__(256) void scanB_kernel(int* __restrict__ bs, int NB) {
    __shared__ int sm[256];
    int t = threadIdx.x;
    int carry = 0;
    for (int b0 = 0; b0 < NB; b0 += 256) {
        int v = (b0 + t < NB) ? bs[b0 + t] : 0;
        sm[t] = v; __syncthreads();
        for (int off = 1; off < 256; off <<= 1) {
            int u = (t >= off) ? sm[t - off] : 0;
            __syncthreads();
            sm[t] += u;
            __syncthreads();
        }
        if (b0 + t < NB) bs[b0 + t] = carry + sm[t] - v;
        int tot = sm[255];
        __syncthreads();
        carry += tot;
    }
}

__global__ __launch_bounds__(256) void scanC_kernel(const int* __restrict__ counts, const int* __restrict__ blocksum,
                                                    int* __restrict__ row_start, int* __restrict__ fillc,
                                                    float* __restrict__ dinv, int N) {
    __shared__ int sm[256];
    int t = threadIdx.x;
    int i = blockIdx.x * 256 + t;
    int v = (i < N) ? counts[i] : 0;
    sm[t] = v; __syncthreads();
    for (int off = 1; off < 256; off <<= 1) {
        int u = (t >= off) ? sm[t - off] : 0;
        __syncthreads();
        sm[t] += u;
        __syncthreads();
    }
    if (i < N) {
        int rsv = blocksum[blockIdx.x] + sm[t] - v;
        row_start[i] = rsv;
        fillc[i] = rsv;
        dinv[i] = rsqrtf((float)v);   // v >= 1 due to self-loop
    }
    if (i == N - 1) row_start[N] = blocksum[blockIdx.x] + sm[t];
}

__global__ void fill_kernel(const int* __restrict__ ei, int* __restrict__ fillc,
                            int* __restrict__ srcs, int E, int E2) {
    int i = blockIdx.x * blockDim.x + threadIdx.x;
    if (i >= E2) return;
    int src, dst;
    if (i < E) { src = ei[i]; dst = ei[E + i]; }
    else       { src = i - E; dst = i - E; }
    int pos = atomicAdd(&fillc[dst], 1);
    srcs[pos] = src;
}

// ---------------- prep: pack W1 into B-fragment order, bf16 ----------------
// Wb[((kk*16 + t)*64 + lane)*8 + j] = bf16(W1[(kk*32 + (lane>>4)*8 + j)*256 + t*16 + (lane&15)])
__global__ __launch_bounds__(256) void prepW_kernel(const float* __restrict__ W1, unsigned short* __restrict__ Wb) {
    int idx = blockIdx.x * 256 + threadIdx.x;     // 32768 total
    int j = idx & 7;
    int lane = (idx >> 3) & 63;
    int t = (idx >> 9) & 15;
    int kk = idx >> 13;
    int k = kk * 32 + (lane >> 4) * 8 + j;
    int n = t * 16 + (lane & 15);
    Wb[idx] = f2bf(W1[k * 256 + n]);
}

// ---------------- GEMM1 via MFMA bf16: h1b[M,256] = bf16(x) @ bf16(W1) ----------------
// wave w: rows [blk*64 + w*16, +16); 16 col-tiles of 16; K=128 in 4 mfma steps.
__global__ __launch_bounds__(256) void gemm1_kernel(const float* __restrict__ x, const unsigned short* __restrict__ Wb,
                                                    unsigned short* __restrict__ h1b, int M) {
    int w = threadIdx.x >> 6, lane = threadIdx.x & 63;
    int quad = lane >> 4, c = lane & 15;
    int rowA = blockIdx.x * 64 + w * 16 + c;       // A operand: m = lane&15
    int rowAc = rowA < M ? rowA : M - 1;
    f32x4 acc[16];
    #pragma unroll
    for (int t = 0; t < 16; t++) acc[t] = (f32x4){0.f, 0.f, 0.f, 0.f};
    #pragma unroll
    for (int kk = 0; kk < 4; kk++) {
        const float* ap = &x[(size_t)rowAc * 128 + kk * 32 + quad * 8];
        float4 a0 = *(const float4*)ap;
        float4 a1 = *(const float4*)(ap + 4);
        union { bf16x8 v; unsigned int u[4]; } af;
        af.u[0] = pack2bf(a0.x, a0.y); af.u[1] = pack2bf(a0.z, a0.w);
        af.u[2] = pack2bf(a1.x, a1.y); af.u[3] = pack2bf(a1.z, a1.w);
        const bf16x8* bp = (const bf16x8*)&Wb[(size_t)(kk * 16) * 512 + lane * 8];
        #pragma unroll
        for (int t = 0; t < 16; t++) {
            bf16x8 bf = bp[t * 64];     // ((kk*16+t)*64 + lane)*8
            acc[t] = __builtin_amdgcn_mfma_f32_16x16x32_bf16(af.v, bf, acc[t], 0, 0, 0);
        }
    }
    // D: row = quad*4 + r, col = t*16 + c
    int growb = blockIdx.x * 64 + w * 16 + quad * 4;
    #pragma unroll
    for (int r = 0; r < 4; r++) {
        int grow = growb + r;
        if (grow < M) {
            #pragma unroll
            for (int t = 0; t < 16; t++)
                h1b[(size_t)grow * 256 + t * 16 + c] = f2bf(acc[t][r]);
        }
    }
}

// ---------------- alpha1 from bf16 h1 ----------------
__global__ void alpha1_kernel(const unsigned short* __restrict__ h1b, const float* __restrict__ a_src,
                              const float* __restrict__ a_dst, float* __restrict__ asrc,
                              float* __restrict__ adst, int N) {
    int i = blockIdx.x * blockDim.x + threadIdx.x;
    if (i >= N * 8) return;
    int h = i & 7;
    const uint4* hp = (const uint4*)&h1b[(size_t)i * 32];   // n*256 + h*32 == i*32
    const float* as = &a_src[h * 32];
    const float* ad = &a_dst[h * 32];
    float s1 = 0.f, s2 = 0.f;
    #pragma unroll
    for (int u4 = 0; u4 < 4; u4++) {
        uint4 vv = hp[u4];
        int f = u4 * 8;
        float v0 = bflo(vv.x), v1 = bfhi(vv.x), v2 = bflo(vv.y), v3 = bfhi(vv.y);
        float v4 = bflo(vv.z), v5 = bfhi(vv.z), v6 = bflo(vv.w), v7 = bfhi(vv.w);
        s1 += v0 * as[f+0] + v1 * as[f+1] + v2 * as[f+2] + v3 * as[f+3]
            + v4 * as[f+4] + v5 * as[f+5] + v6 * as[f+6] + v7 * as[f+7];
        s2 += v0 * ad[f+0] + v1 * ad[f+1] + v2 * ad[f+2] + v3 * ad[f+3]
            + v4 * ad[f+4] + v5 * ad[f+5] + v6 * ad[f+6] + v7 * ad[f+7];
    }
    asrc[i] = s1; adst[i] = s2;
}

// ---------------- agg1: wave/node, bf16 gathers (8B/lane), 16 in flight ----------------
__global__ __launch_bounds__(256) void agg1_kernel(const unsigned short* __restrict__ h1b, const float* __restrict__ asrc,
                                                   const float* __restrict__ adst, const int* __restrict__ row_start,
                                                   const int* __restrict__ srcs, const float* __restrict__ b1,
                                                   float* __restrict__ h1p, int N) {
    int node = blockIdx.x * 4 + (threadIdx.x >> 6);
    if (node >= N) return;
    int lane = threadIdx.x & 63;
    int h = lane >> 3, e8 = lane & 7;
    float adn = adst[node * 8 + h];
    int rs = row_start[node], re = row_start[node + 1];
    float4 acc = make_float4(0.f, 0.f, 0.f, 0.f);
    float den = 0.f;
    int o4 = lane * 4;
    for (int base = rs; base < re; base += 64) {
        int cnt = re - base; if (cnt > 64) cnt = 64;
        int sv = __builtin_nontemporal_load(&srcs[base + (lane < cnt ? lane : 0)]);
        int g = 0;
        for (; g + 16 <= cnt; g += 16) {
            int ssA = __shfl(sv, g + e8);
            int ssB = __shfl(sv, g + 8 + e8);
            float wA = __expf(lrelu(asrc[ssA * 8 + h] + adn));
            float wB = __expf(lrelu(asrc[ssB * 8 + h] + adn));
            uint2 v[16];
            #pragma unroll
            for (int q = 0; q < 16; q++) {
                int s = __shfl(sv, g + q);
                v[q] = *(const uint2*)&h1b[(size_t)s * 256 + o4];
            }
            #pragma unroll
            for (int q = 0; q < 8; q++) {
                float w = __shfl(wA, (h << 3) | q);
                acc.x += w * bflo(v[q].x); acc.y += w * bfhi(v[q].x);
                acc.z += w * bflo(v[q].y); acc.w += w * bfhi(v[q].y);
                den += w;
            }
            #pragma unroll
            for (int q = 8; q < 16; q++) {
                float w = __shfl(wB, (h << 3) | (q - 8));
                acc.x += w * bflo(v[q].x); acc.y += w * bfhi(v[q].x);
                acc.z += w * bflo(v[q].y); acc.w += w * bfhi(v[q].y);
                den += w;
            }
        }
        if (g + 8 <= cnt) {
            int ss = __shfl(sv, g + e8);
            float wp = __expf(lrelu(asrc[ss * 8 + h] + adn));
            uint2 v[8];
            #pragma unroll
            for (int q = 0; q < 8; q++) {
                int s = __shfl(sv, g + q);
                v[q] = *(const uint2*)&h1b[(size_t)s * 256 + o4];
            }
            #pragma unroll
            for (int q = 0; q < 8; q++) {
                float w = __shfl(wp, (h << 3) | q);
                acc.x += w * bflo(v[q].x); acc.y += w * bfhi(v[q].x);
                acc.z += w * bflo(v[q].y); acc.w += w * bfhi(v[q].y);
                den += w;
            }
            g += 8;
        }
        if (g < cnt) {
            int ep = g + e8;
            int epc = ep < cnt - 1 ? ep : cnt - 1;
            int ss = __shfl(sv, epc);
            float wp = (ep < cnt) ? __expf(lrelu(asrc[ss * 8 + h] + adn)) : 0.f;
            #pragma unroll
            for (int q = 0; q < 8; q++) {
                if (g + q < cnt) {   // wave-uniform
                    int s = __shfl(sv, g + q);
                    float w = __shfl(wp, (h << 3) | q);
                    uint2 vv = *(const uint2*)&h1b[(size_t)s * 256 + o4];
                    acc.x += w * bflo(vv.x); acc.y += w * bfhi(vv.x);
                    acc.z += w * bflo(vv.y); acc.w += w * bfhi(vv.y);
                    den += w;
                }
            }
        }
    }
    float inv = 1.f / den;
    f32x4 r;
    r.x = elu1(acc.x * inv + b1[o4 + 0]);
    r.y = elu1(acc.y * inv + b1[o4 + 1]);
    r.z = elu1(acc.z * inv + b1[o4 + 2]);
    r.w = elu1(acc.w * inv + b1[o4 + 3]);
    __builtin_nontemporal_store(r, (f32x4*)&h1p[(size_t)node * 256 + o4]);
}

// ---------------- GEMM2 + alpha2: register-resident W2, broadcast X reads ----------------
__global__ __launch_bounds__(256) void gemm2_kernel(const float* __restrict__ X, const float* __restrict__ W2,
                                                    const float* __restrict__ a_src2, const float* __restrict__ a_dst2,
                                                    float* __restrict__ h2, float* __restrict__ asrc2,
                                                    float* __restrict__ adst2, int N) {
    int lane = threadIdx.x & 63;
    int c = lane & 15, kq = lane >> 4;
    int wid = blockIdx.x * (blockDim.x >> 6) + (threadIdx.x >> 6);
    int nwaves = gridDim.x * (blockDim.x >> 6);
    float w2r[64];
    #pragma unroll
    for (int i = 0; i < 64; i++) w2r[i] = W2[(kq * 64 + i) * 16 + c];
    float as_c = a_src2[c], ad_c = a_dst2[c];
    for (int n = wid; n < N; n += nwaves) {
        const float* xp = &X[(size_t)n * 256 + kq * 64];
        float acc = 0.f;
        #pragma unroll
        for (int i4 = 0; i4 < 16; i4++) {
            float4 xv = *(const float4*)&xp[i4 * 4];
            acc += xv.x * w2r[i4 * 4] + xv.y * w2r[i4 * 4 + 1] + xv.z * w2r[i4 * 4 + 2] + xv.w * w2r[i4 * 4 + 3];
        }
        acc += __shfl_xor(acc, 16);
        acc += __shfl_xor(acc, 32);
        float s1 = acc * as_c, s2 = acc * ad_c;
        #pragma unroll
        for (int off = 1; off < 16; off <<= 1) { s1 += __shfl_xor(s1, off); s2 += __shfl_xor(s2, off); }
        if (kq == 0) h2[n * 16 + c] = acc;
        if (lane == 0) { asrc2[n] = s1; adst2[n] = s2; }
    }
}

// ---------------- agg2 + fused gemm3: 16 gathers in flight ----------------
__global__ __launch_bounds__(256) void agg2_kernel(const float* __restrict__ h2, const float* __restrict__ asrc2,
                                                   const float* __restrict__ adst2, const int* __restrict__ row_start,
                                                   const int* __restrict__ srcs, const float* __restrict__ b2,
                                                   const float* __restrict__ W3, float* __restrict__ h4, int N) {
    int node = blockIdx.x * 4 + (threadIdx.x >> 6);
    if (node >= N) return;
    int lane = threadIdx.x & 63;
    int q = lane >> 4, c = lane & 15;
    float adn = adst2[node];
    int rs = row_start[node], re = row_start[node + 1];
    float acc = 0.f, den = 0.f;
    for (int base = rs; base < re; base += 64) {
        int cnt = re - base; if (cnt > 64) cnt = 64;
        int sv = 0; float wv = 0.f;
        if (lane < cnt) { sv = __builtin_nontemporal_load(&srcs[base + lane]); wv = __expf(lrelu(asrc2[sv] + adn)); }
        int nit = (cnt + 3) >> 2;
        int it = 0;
        for (; it + 4 <= nit; it += 4) {     // 16 edges in flight
            int s0 = __shfl(sv, it * 4 + q),       s1 = __shfl(sv, (it + 1) * 4 + q);
            int s2 = __shfl(sv, (it + 2) * 4 + q), s3 = __shfl(sv, (it + 3) * 4 + q);
            float w0 = __shfl(wv, it * 4 + q),       w1 = __shfl(wv, (it + 1) * 4 + q);
            float w2 = __shfl(wv, (it + 2) * 4 + q), w3 = __shfl(wv, (it + 3) * 4 + q);
            float v0 = h2[s0 * 16 + c], v1 = h2[s1 * 16 + c];
            float v2 = h2[s2 * 16 + c], v3 = h2[s3 * 16 + c];
            acc += w0 * v0 + w1 * v1 + w2 * v2 + w3 * v3;
            den += (w0 + w1) + (w2 + w3);
        }
        for (; it < nit; it++) {
            int j = it * 4 + q;
            int s = __shfl(sv, j);
            float w = __shfl(wv, j);     // 0 for j >= cnt
            acc += w * h2[s * 16 + c]; den += w;
        }
    }
    acc += __shfl_xor(acc, 16); acc += __shfl_xor(acc, 32);
    den += __shfl_xor(den, 16); den += __shfl_xor(den, 32);
    float h3v = elu1(acc / den + b2[c]);     // identical across q groups
    float h4v = 0.f;
    #pragma unroll
    for (int cs = 0; cs < 16; cs++) {
        float hv = __shfl(h3v, cs);
        h4v += hv * W3[cs * 16 + c];
    }
    if (q == 0) h4[node * 16 + c] = h4v;
}

// ---------------- agg3 (GCN): 16 gathers in flight ----------------
__global__ __launch_bounds__(256) void agg3_kernel(const float* __restrict__ h4, const float* __restrict__ dinv,
                                                   const int* __restrict__ row_start, const int* __restrict__ srcs,
                                                   const float* __restrict__ b3, float* __restrict__ out, int N) {
    int node = blockIdx.x * 4 + (threadIdx.x >> 6);
    if (node >= N) return;
    int lane = threadIdx.x & 63;
    int q = lane >> 4, c = lane & 15;
    int rs = row_start[node], re = row_start[node + 1];
    float acc = 0.f;
    for (int base = rs; base < re; base += 64) {
        int cnt = re - base; if (cnt > 64) cnt = 64;
        int sv = 0; float wv = 0.f;
        if (lane < cnt) { sv = __builtin_nontemporal_load(&srcs[base + lane]); wv = dinv[sv]; }
        int nit = (cnt + 3) >> 2;
        int it = 0;
        for (; it + 4 <= nit; it += 4) {
            int s0 = __shfl(sv, it * 4 + q),       s1 = __shfl(sv, (it + 1) * 4 + q);
            int s2 = __shfl(sv, (it + 2) * 4 + q), s3 = __shfl(sv, (it + 3) * 4 + q);
            float w0 = __shfl(wv, it * 4 + q),       w1 = __shfl(wv, (it + 1) * 4 + q);
            float w2 = __shfl(wv, (it + 2) * 4 + q), w3 = __shfl(wv, (it + 3) * 4 + q);
            float v0 = h4[s0 * 16 + c], v1 = h4[s1 * 16 + c];
            float v2 = h4[s2 * 16 + c], v3 = h4[s3 * 16 + c];
            acc += w0 * v0 + w1 * v1 + w2 * v2 + w3 * v3;
        }
        for (; it < nit; it++) {
            int j = it * 4 + q;
            int s = __shfl(sv, j);
            float w = __shfl(wv, j);
            acc += w * h4[s * 16 + c];
        }
    }
    acc += __shfl_xor(acc, 16); acc += __shfl_xor(acc, 32);
    if (q == 0) out[node * 16 + c] = acc * dinv[node] + b3[c];
}

extern "C" void kernel_launch(void* const* d_in, const int* in_sizes, int n_in,
                              void* d_out, int out_size, void* d_ws, size_t ws_size,
                              hipStream_t stream) {
    const float* x      = (const float*)d_in[0];
    const int*   ei     = (const int*)d_in[1];
    const float* W1     = (const float*)d_in[2];
    const float* a_src1 = (const float*)d_in[3];
    const float* a_dst1 = (const float*)d_in[4];
    const float* b1     = (const float*)d_in[5];
    const float* W2     = (const float*)d_in[6];
    const float* a_src2 = (const float*)d_in[7];
    const float* a_dst2 = (const float*)d_in[8];
    const float* b2     = (const float*)d_in[9];
    const float* W3     = (const float*)d_in[10];
    const float* b3     = (const float*)d_in[11];
    float* out = (float*)d_out;

    const int N  = in_sizes[0] / 128;   // 50000
    const int E  = in_sizes[1] / 2;     // 800000
    const int E2 = E + N;
    const int NB = (N + 255) / 256;

    char* p = (char*)d_ws;
    auto alloc = [&](size_t bytes) -> void* {
        void* r = (void*)p;
        p += (bytes + 255) & ~(size_t)255;
        return r;
    };
    int*   counts = (int*)alloc((size_t)N * 4);
    int*   rowst  = (int*)alloc((size_t)(N + 1) * 4);
    int*   fillc  = (int*)alloc((size_t)N * 4);
    int*   srcs   = (int*)alloc((size_t)E2 * 4);
    int*   bsum   = (int*)alloc((size_t)NB * 4);
    unsigned short* Wb  = (unsigned short*)alloc((size_t)32768 * 2);
    unsigned short* h1b = (unsigned short*)alloc((size_t)N * 256 * 2);
    float* h1p    = (float*)alloc((size_t)N * 256 * 4);
    float* as1    = (float*)alloc((size_t)N * 8 * 4);
    float* ad1    = (float*)alloc((size_t)N * 8 * 4);
    float* h2     = (float*)alloc((size_t)N * 16 * 4);
    float* as2    = (float*)alloc((size_t)N * 4);
    float* ad2    = (float*)alloc((size_t)N * 4);
    float* h4     = (float*)alloc((size_t)N * 16 * 4);
    float* dinv   = (float*)alloc((size_t)N * 4);

    (void)hipMemsetAsync(counts, 0, (size_t)N * 4, stream);

    count_kernel<<<(E2 + 255) / 256, 256, 0, stream>>>(ei, counts, E, E2);
    scanA_kernel<<<NB, 256, 0, stream>>>(counts, bsum, N);
    scanB_kernel<<<1, 256, 0, stream>>>(bsum, NB);
    scanC_kernel<<<NB, 256, 0, stream>>>(counts, bsum, rowst, fillc, dinv, N);
    fill_kernel<<<(E2 + 255) / 256, 256, 0, stream>>>(ei, fillc, srcs, E, E2);

    prepW_kernel<<<128, 256, 0, stream>>>(W1, Wb);
    gemm1_kernel<<<(N + 63) / 64, 256, 0, stream>>>(x, Wb, h1b, N);
    alpha1_kernel<<<(N * 8 + 255) / 256, 256, 0, stream>>>(h1b, a_src1, a_dst1, as1, ad1, N);
    agg1_kernel<<<(N + 3) / 4, 256, 0, stream>>>(h1b, as1, ad1, rowst, srcs, b1, h1p, N);

    gemm2_kernel<<<1024, 256, 0, stream>>>(h1p, W2, a_src2, a_dst2, h2, as2, ad2, N);
    agg2_kernel<<<(N + 3) / 4, 256, 0, stream>>>(h2, as2, ad2, rowst, srcs, b2, W3, h4, N);

    agg3_kernel<<<(N + 3) / 4, 256, 0, stream>>>(h4, dinv, rowst, srcs, b3, out, N);
}